// Round 1
// baseline (2291.649 us; speedup 1.0000x reference)
//
#include <hip/hip_runtime.h>
#include <hip/hip_bf16.h>
#include <math.h>

#define H 300
#define WAVE 64

// ---------------------------------------------------------------------------
// l2 normalize rows: one wave per row
// ---------------------------------------------------------------------------
__global__ void k_l2norm(const float* __restrict__ x, float* __restrict__ out, int n) {
    int wave = blockIdx.x * (blockDim.x / WAVE) + (threadIdx.x >> 6);
    int lane = threadIdx.x & 63;
    if (wave >= n) return;
    const float* row = x + (long)wave * H;
    float s = 0.f;
    for (int j = lane; j < H; j += WAVE) { float v = row[j]; s += v * v; }
    for (int o = 32; o > 0; o >>= 1) s += __shfl_xor(s, o);
    float nrm = sqrtf(s);
    float sc = 1.0f / fmaxf(nrm, 1e-12f);
    float* orow = out + (long)wave * H;
    for (int j = lane; j < H; j += WAVE) orow[j] = row[j] * sc;
}

// ---------------------------------------------------------------------------
// zero int buffer
// ---------------------------------------------------------------------------
__global__ void k_zero_int(int* p, int n) {
    int i = blockIdx.x * blockDim.x + threadIdx.x;
    int stride = gridDim.x * blockDim.x;
    for (; i < n; i += stride) p[i] = 0;
}

// ---------------------------------------------------------------------------
// degree count (in-degree over ei_i)
// ---------------------------------------------------------------------------
__global__ void k_count_deg(const int* __restrict__ ei_i, int* __restrict__ deg, int E) {
    int i = blockIdx.x * blockDim.x + threadIdx.x;
    int stride = gridDim.x * blockDim.x;
    for (; i < E; i += stride) atomicAdd(&deg[ei_i[i]], 1);
}

// ---------------------------------------------------------------------------
// dinv = deg > 0 ? deg^-0.5 : 0
// ---------------------------------------------------------------------------
__global__ void k_dinv(const int* __restrict__ deg, float* __restrict__ dinv, int n) {
    int i = blockIdx.x * blockDim.x + threadIdx.x;
    int stride = gridDim.x * blockDim.x;
    for (; i < n; i += stride) {
        int d = deg[i];
        dinv[i] = (d > 0) ? 1.0f / sqrtf((float)d) : 0.0f;
    }
}

// ---------------------------------------------------------------------------
// exclusive prefix scan of deg -> offsets (n+1), also cursor[i] = offsets[i]
// single block of 1024 threads
// ---------------------------------------------------------------------------
__global__ void k_scan(const int* __restrict__ deg, int* __restrict__ offsets,
                       int* __restrict__ cursor, int n) {
    __shared__ int sh[1024];
    __shared__ int carry_sh;
    int tid = threadIdx.x;
    if (tid == 0) carry_sh = 0;
    __syncthreads();
    for (int base = 0; base < n; base += 1024) {
        int v = (base + tid < n) ? deg[base + tid] : 0;
        sh[tid] = v;
        __syncthreads();
        for (int off = 1; off < 1024; off <<= 1) {
            int add = (tid >= off) ? sh[tid - off] : 0;
            __syncthreads();
            sh[tid] += add;
            __syncthreads();
        }
        int total = sh[1023];
        int exc = sh[tid] - v;
        int carry = carry_sh;
        if (base + tid < n) {
            int o = carry + exc;
            offsets[base + tid] = o;
            cursor[base + tid] = o;
        }
        __syncthreads();
        if (tid == 0) carry_sh = carry + total;
        __syncthreads();
    }
    if (tid == 0) offsets[n] = carry_sh;
}

// ---------------------------------------------------------------------------
// CSR fill: csr_src[pos] = src, grouped by destination
// ---------------------------------------------------------------------------
__global__ void k_fill_csr(const int* __restrict__ ei_j, const int* __restrict__ ei_i,
                           int* __restrict__ cursor, int* __restrict__ csr_src, int E) {
    int i = blockIdx.x * blockDim.x + threadIdx.x;
    int stride = gridDim.x * blockDim.x;
    for (; i < E; i += stride) {
        int dst = ei_i[i];
        int pos = atomicAdd(&cursor[dst], 1);
        csr_src[pos] = ei_j[i];
    }
}

// ---------------------------------------------------------------------------
// Tiled fp32 NT GEMM: out[n,k] = sum_j X[n,j] * W[k,j]
// X: n_rows x 300, W: 300 x 300, out: n_rows x 300
// BM=BN=64, BK=20, block=256 (16x16 threads, 4x4 microtile)
// ---------------------------------------------------------------------------
__global__ __launch_bounds__(256) void k_gemm_nt(const float* __restrict__ X,
                                                 const float* __restrict__ W,
                                                 float* __restrict__ out, int n_rows) {
    __shared__ __align__(16) float As[20][68];
    __shared__ __align__(16) float Bs[20][68];
    int bm = blockIdx.x * 64;
    int bn = blockIdx.y * 64;
    int tid = threadIdx.x;
    int tx = tid & 15, ty = tid >> 4;
    float acc[4][4] = {};
    for (int k0 = 0; k0 < H; k0 += 20) {
        #pragma unroll
        for (int l = 0; l < 5; ++l) {
            int idx = tid + l * 256;
            int r = idx / 20, c = idx % 20;
            int gr = bm + r;
            As[c][r] = (gr < n_rows) ? X[(long)gr * H + k0 + c] : 0.f;
            int gk = bn + r;
            Bs[c][r] = (gk < H) ? W[(long)gk * H + k0 + c] : 0.f;
        }
        __syncthreads();
        #pragma unroll
        for (int kk = 0; kk < 20; ++kk) {
            float4 a4 = *(const float4*)&As[kk][ty * 4];
            float4 b4 = *(const float4*)&Bs[kk][tx * 4];
            float a[4] = {a4.x, a4.y, a4.z, a4.w};
            float b[4] = {b4.x, b4.y, b4.z, b4.w};
            #pragma unroll
            for (int u = 0; u < 4; u++)
                #pragma unroll
                for (int v = 0; v < 4; v++) acc[u][v] += a[u] * b[v];
        }
        __syncthreads();
    }
    #pragma unroll
    for (int u = 0; u < 4; u++) {
        int gr = bm + ty * 4 + u;
        if (gr >= n_rows) continue;
        #pragma unroll
        for (int v = 0; v < 4; v++) {
            int gc = bn + tx * 4 + v;
            if (gc >= H) continue;
            out[(long)gr * H + gc] = acc[u][v];
        }
    }
}

// ---------------------------------------------------------------------------
// GCN gather: out[i,:] = relu( sum_{e:dst=i} dinv[i]*dinv[src] * h[src,:] )
// one block (256 thr) per node; cols t and t+256
// ---------------------------------------------------------------------------
__global__ __launch_bounds__(256) void k_gcn_gather(const float* __restrict__ h,
                                                    const float* __restrict__ dinv,
                                                    const int* __restrict__ offsets,
                                                    const int* __restrict__ csr_src,
                                                    float* __restrict__ out) {
    int i = blockIdx.x;
    int t = threadIdx.x;
    int start = offsets[i], end = offsets[i + 1];
    float di = dinv[i];
    float acc0 = 0.f, acc1 = 0.f;
    __shared__ float wsh[256];
    __shared__ int ssh[256];
    for (int cbase = start; cbase < end; cbase += 256) {
        int p = cbase + t;
        if (p < end) {
            int j = csr_src[p];
            ssh[t] = j;
            wsh[t] = di * dinv[j];
        }
        __syncthreads();
        int cnt = min(256, end - cbase);
        for (int q = 0; q < cnt; q++) {
            float w = wsh[q];
            const float* row = h + (long)ssh[q] * H;
            acc0 += w * row[t];
            if (t + 256 < H) acc1 += w * row[t + 256];
        }
        __syncthreads();
    }
    float* orow = out + (long)i * H;
    orow[t] = fmaxf(acc0, 0.f);
    if (t + 256 < H) orow[t + 256] = fmaxf(acc1, 0.f);
}

// ---------------------------------------------------------------------------
// dual dot: s_i[n] = dot(x[n], ai), s_j[n] = dot(x[n], aj); one wave per row
// ---------------------------------------------------------------------------
__global__ void k_dual_dot(const float* __restrict__ x, long x_stride,
                           const float* __restrict__ ai, const float* __restrict__ aj,
                           float* __restrict__ s_i, float* __restrict__ s_j, int n) {
    int wave = blockIdx.x * (blockDim.x / WAVE) + (threadIdx.x >> 6);
    int lane = threadIdx.x & 63;
    if (wave >= n) return;
    const float* row = x + (long)wave * x_stride;
    float d0 = 0.f, d1 = 0.f;
    for (int j = lane; j < H; j += WAVE) {
        float v = row[j];
        d0 += v * ai[j];
        d1 += v * aj[j];
    }
    for (int o = 32; o > 0; o >>= 1) { d0 += __shfl_down(d0, o); d1 += __shfl_down(d1, o); }
    if (lane == 0) { s_i[wave] = d0; s_j[wave] = d1; }
}

// ---------------------------------------------------------------------------
// GAT gather with fused segment softmax.
// out[i,:] = relu( sum_e alpha_e * x[src_e,:] )
// alpha_e = exp(leaky(s_i[i]+s_j[src]) - m_i) / (denom_i + 1e-16)
// ---------------------------------------------------------------------------
__global__ __launch_bounds__(256) void k_gat_gather(const float* __restrict__ x, long x_stride,
                                                    const float* __restrict__ s_i_arr,
                                                    const float* __restrict__ s_j_arr,
                                                    const int* __restrict__ offsets,
                                                    const int* __restrict__ csr_src,
                                                    float* __restrict__ out, long out_stride,
                                                    int out_off) {
    int i = blockIdx.x;
    int t = threadIdx.x;
    int start = offsets[i], end = offsets[i + 1];
    float acc0 = 0.f, acc1 = 0.f;
    __shared__ float red[256];
    __shared__ float wsh[256];
    __shared__ int ssh[256];
    if (start < end) {
        float si = s_i_arr[i];
        // phase 0a: segment max
        float lm = -1e30f;
        for (int p = start + t; p < end; p += 256) {
            float sc = si + s_j_arr[csr_src[p]];
            sc = (sc >= 0.f) ? sc : 0.01f * sc;
            lm = fmaxf(lm, sc);
        }
        red[t] = lm;
        __syncthreads();
        for (int o = 128; o > 0; o >>= 1) {
            if (t < o) red[t] = fmaxf(red[t], red[t + o]);
            __syncthreads();
        }
        float m = red[0];
        __syncthreads();
        // phase 0b: denom
        float ls = 0.f;
        for (int p = start + t; p < end; p += 256) {
            float sc = si + s_j_arr[csr_src[p]];
            sc = (sc >= 0.f) ? sc : 0.01f * sc;
            ls += expf(sc - m);
        }
        red[t] = ls;
        __syncthreads();
        for (int o = 128; o > 0; o >>= 1) {
            if (t < o) red[t] += red[t + o];
            __syncthreads();
        }
        float inv_denom = 1.0f / (red[0] + 1e-16f);
        __syncthreads();
        // phase 1: weighted gather, chunked
        for (int cbase = start; cbase < end; cbase += 256) {
            int p = cbase + t;
            if (p < end) {
                int j = csr_src[p];
                float sc = si + s_j_arr[j];
                sc = (sc >= 0.f) ? sc : 0.01f * sc;
                ssh[t] = j;
                wsh[t] = expf(sc - m) * inv_denom;
            }
            __syncthreads();
            int cnt = min(256, end - cbase);
            for (int q = 0; q < cnt; q++) {
                float w = wsh[q];
                const float* row = x + (long)ssh[q] * x_stride;
                acc0 += w * row[t];
                if (t + 256 < H) acc1 += w * row[t + 256];
            }
            __syncthreads();
        }
    }
    float* orow = out + (long)i * out_stride + out_off;
    orow[t] = fmaxf(acc0, 0.f);
    if (t + 256 < H) orow[t + 256] = fmaxf(acc1, 0.f);
}

// ---------------------------------------------------------------------------
// highway elementwise: out[row*out_stride+col] = g*xnew + (1-g)*xold
// g = sigmoid(pre + b[col])
// ---------------------------------------------------------------------------
__global__ void k_highway(const float* __restrict__ pre, const float* __restrict__ b,
                          const float* __restrict__ xnew, const float* __restrict__ xold,
                          float* __restrict__ out, long out_stride, int n_rows) {
    long total = (long)n_rows * H;
    long stride = (long)gridDim.x * blockDim.x;
    for (long idx = (long)blockIdx.x * blockDim.x + threadIdx.x; idx < total; idx += stride) {
        long row = idx / H;
        int col = (int)(idx - row * H);
        float g = 1.0f / (1.0f + expf(-(pre[idx] + b[col])));
        out[row * out_stride + col] = g * xnew[idx] + (1.0f - g) * xold[idx];
    }
}

// ---------------------------------------------------------------------------
// launch
// ---------------------------------------------------------------------------
extern "C" void kernel_launch(void* const* d_in, const int* in_sizes, int n_in,
                              void* d_out, int out_size, void* d_ws, size_t ws_size,
                              hipStream_t stream) {
    const float* x_e     = (const float*)d_in[0];
    const int*   ei_all  = (const int*)d_in[3];
    const float* gcn1_W  = (const float*)d_in[5];
    const float* hw1_W   = (const float*)d_in[6];
    const float* hw1_b   = (const float*)d_in[7];
    const float* gat1_ai = (const float*)d_in[8];
    const float* gat1_aj = (const float*)d_in[9];
    const float* ghw1_W  = (const float*)d_in[10];
    const float* ghw1_b  = (const float*)d_in[11];
    const float* gat2_ai = (const float*)d_in[12];
    const float* gat2_aj = (const float*)d_in[13];
    const float* ghw2_W  = (const float*)d_in[14];
    const float* ghw2_b  = (const float*)d_in[15];
    const float* gat_ai  = (const float*)d_in[16];
    const float* gat_aj  = (const float*)d_in[17];

    const int N = in_sizes[0] / H;
    const int E = in_sizes[3] / 2;
    const int* ei_j = ei_all;
    const int* ei_i = ei_all + E;

    float* out = (float*)d_out;

    // workspace layout
    size_t NH = (size_t)N * H;
    float* A      = (float*)d_ws;       // x0, later gate-pre / x3
    float* B      = A + NH;             // h / gat outputs
    float* C      = B + NH;             // gcn_out -> x2
    float* sbi    = C + NH;             // s_i
    float* sbj    = sbi + N;            // s_j
    float* dinv   = sbj + N;
    int*   deg    = (int*)(dinv + N);
    int*   offs   = deg + N;            // N+1
    int*   cursor = offs + (N + 1);
    int*   csr    = cursor + N;         // E

    dim3 blk256(256);
    int rowsPerBlock = 256 / WAVE;
    dim3 gridRows((N + rowsPerBlock - 1) / rowsPerBlock);
    dim3 gridNode(N);
    dim3 gridE(2048);
    dim3 gridEW(2048);
    dim3 gridGemm((N + 63) / 64, (H + 63) / 64);

    // 1. x0 = l2_normalize(x_e) -> A
    hipLaunchKernelGGL(k_l2norm, gridRows, blk256, 0, stream, x_e, A, N);

    // 2. CSR build
    hipLaunchKernelGGL(k_zero_int, dim3(256), blk256, 0, stream, deg, N);
    hipLaunchKernelGGL(k_count_deg, gridE, blk256, 0, stream, ei_i, deg, E);
    hipLaunchKernelGGL(k_dinv, dim3(256), blk256, 0, stream, deg, dinv, N);
    hipLaunchKernelGGL(k_scan, dim3(1), dim3(1024), 0, stream, deg, offs, cursor, N);
    hipLaunchKernelGGL(k_fill_csr, gridE, blk256, 0, stream, ei_j, ei_i, cursor, csr, E);

    // 3. h = x0 @ gcn1_W.T -> B
    hipLaunchKernelGGL(k_gemm_nt, gridGemm, blk256, 0, stream, A, gcn1_W, B, N);

    // 4. gcn_out -> C
    hipLaunchKernelGGL(k_gcn_gather, gridNode, blk256, 0, stream, B, dinv, offs, csr, C);

    // 5. gate-pre = x0 @ hw1_W.T -> B ; x2 = hw(x0, gcn_out) -> C
    hipLaunchKernelGGL(k_gemm_nt, gridGemm, blk256, 0, stream, A, hw1_W, B, N);
    hipLaunchKernelGGL(k_highway, gridEW, blk256, 0, stream, B, hw1_b, C, A, C, (long)H, N);

    // 6. GAT1: input C (x2) -> B
    hipLaunchKernelGGL(k_dual_dot, gridRows, blk256, 0, stream, C, (long)H, gat1_ai, gat1_aj, sbi, sbj, N);
    hipLaunchKernelGGL(k_gat_gather, gridNode, blk256, 0, stream, C, (long)H, sbi, sbj, offs, csr, B, (long)H, 0);

    // 7. gate-pre = x2 @ ghw1_W.T -> A ; x3 = hw(x2, gat1_out) -> A
    hipLaunchKernelGGL(k_gemm_nt, gridGemm, blk256, 0, stream, C, ghw1_W, A, N);
    hipLaunchKernelGGL(k_highway, gridEW, blk256, 0, stream, A, ghw1_b, B, C, A, (long)H, N);

    // 8. GAT2: input A (x3) -> B
    hipLaunchKernelGGL(k_dual_dot, gridRows, blk256, 0, stream, A, (long)H, gat2_ai, gat2_aj, sbi, sbj, N);
    hipLaunchKernelGGL(k_gat_gather, gridNode, blk256, 0, stream, A, (long)H, sbi, sbj, offs, csr, B, (long)H, 0);

    // 9. gate-pre = x2 @ ghw2_W.T -> A ; xe = hw(x2, gat2_out) -> d_out[:, 0:300] (stride 600)
    hipLaunchKernelGGL(k_gemm_nt, gridGemm, blk256, 0, stream, C, ghw2_W, A, N);
    hipLaunchKernelGGL(k_highway, gridEW, blk256, 0, stream, A, ghw2_b, B, C, out, (long)(2 * H), N);

    // 10. final GAT on xe (in d_out, stride 600) -> d_out[:, 300:600]
    hipLaunchKernelGGL(k_dual_dot, gridRows, blk256, 0, stream, out, (long)(2 * H), gat_ai, gat_aj, sbi, sbj, N);
    hipLaunchKernelGGL(k_gat_gather, gridNode, blk256, 0, stream, out, (long)(2 * H), sbi, sbj, offs, csr, out, (long)(2 * H), H);
}

// Round 2
// 1729.249 us; speedup vs baseline: 1.3252x; 1.3252x over previous
//
#include <hip/hip_runtime.h>
#include <hip/hip_bf16.h>
#include <math.h>

#define H 300
#define WAVE 64

typedef short bf16x8 __attribute__((ext_vector_type(8)));
typedef short short4v __attribute__((ext_vector_type(4)));
typedef float f32x4 __attribute__((ext_vector_type(4)));

__device__ inline unsigned short f2b(float f) {
    union { float f; unsigned int u; } x; x.f = f;
    unsigned int r = x.u + 0x7FFF + ((x.u >> 16) & 1);
    return (unsigned short)(r >> 16);
}

// ---------------------------------------------------------------------------
// l2 normalize rows: one wave per row
// ---------------------------------------------------------------------------
__global__ void k_l2norm(const float* __restrict__ x, float* __restrict__ out, int n) {
    int wave = blockIdx.x * (blockDim.x / WAVE) + (threadIdx.x >> 6);
    int lane = threadIdx.x & 63;
    if (wave >= n) return;
    const float* row = x + (long)wave * H;
    float s = 0.f;
    for (int j = lane; j < H; j += WAVE) { float v = row[j]; s += v * v; }
    for (int o = 32; o > 0; o >>= 1) s += __shfl_xor(s, o);
    float nrm = sqrtf(s);
    float sc = 1.0f / fmaxf(nrm, 1e-12f);
    float* orow = out + (long)wave * H;
    for (int j = lane; j < H; j += WAVE) orow[j] = row[j] * sc;
}

__global__ void k_zero_int(int* p, int n) {
    int i = blockIdx.x * blockDim.x + threadIdx.x;
    int stride = gridDim.x * blockDim.x;
    for (; i < n; i += stride) p[i] = 0;
}

__global__ void k_count_deg(const int* __restrict__ ei_i, int* __restrict__ deg, int E) {
    int i = blockIdx.x * blockDim.x + threadIdx.x;
    int stride = gridDim.x * blockDim.x;
    for (; i < E; i += stride) atomicAdd(&deg[ei_i[i]], 1);
}

__global__ void k_dinv(const int* __restrict__ deg, float* __restrict__ dinv, int n) {
    int i = blockIdx.x * blockDim.x + threadIdx.x;
    int stride = gridDim.x * blockDim.x;
    for (; i < n; i += stride) {
        int d = deg[i];
        dinv[i] = (d > 0) ? 1.0f / sqrtf((float)d) : 0.0f;
    }
}

__global__ void k_scan(const int* __restrict__ deg, int* __restrict__ offsets,
                       int* __restrict__ cursor, int n) {
    __shared__ int sh[1024];
    __shared__ int carry_sh;
    int tid = threadIdx.x;
    if (tid == 0) carry_sh = 0;
    __syncthreads();
    for (int base = 0; base < n; base += 1024) {
        int v = (base + tid < n) ? deg[base + tid] : 0;
        sh[tid] = v;
        __syncthreads();
        for (int off = 1; off < 1024; off <<= 1) {
            int add = (tid >= off) ? sh[tid - off] : 0;
            __syncthreads();
            sh[tid] += add;
            __syncthreads();
        }
        int total = sh[1023];
        int exc = sh[tid] - v;
        int carry = carry_sh;
        if (base + tid < n) {
            int o = carry + exc;
            offsets[base + tid] = o;
            cursor[base + tid] = o;
        }
        __syncthreads();
        if (tid == 0) carry_sh = carry + total;
        __syncthreads();
    }
    if (tid == 0) offsets[n] = carry_sh;
}

__global__ void k_fill_csr(const int* __restrict__ ei_j, const int* __restrict__ ei_i,
                           int* __restrict__ cursor, int* __restrict__ csr_src, int E) {
    int i = blockIdx.x * blockDim.x + threadIdx.x;
    int stride = gridDim.x * blockDim.x;
    for (; i < E; i += stride) {
        int dst = ei_i[i];
        int pos = atomicAdd(&cursor[dst], 1);
        csr_src[pos] = ei_j[i];
    }
}

// ---------------------------------------------------------------------------
// bf16 MFMA NT GEMM: out[m,n] = sum_k X[m,k] * W[n,k]   (fp32 in/out)
// BM=128, BN=64, BK=32, 256 threads = 4 waves in 2x2, fp32->bf16 on the fly.
// ---------------------------------------------------------------------------
#define BM 128
#define BN 64
#define BK 32
#define LDP 40   // padded row length (bf16 elems) -> 80B stride

__global__ __launch_bounds__(256) void k_gemm_bf16(const float* __restrict__ X,
                                                   const float* __restrict__ W,
                                                   float* __restrict__ out, int n_rows) {
    __shared__ __align__(16) short As[BM * LDP];
    __shared__ __align__(16) short Bs[BN * LDP];
    const int tid = threadIdx.x;
    const int bm = blockIdx.x * BM;
    const int bn = blockIdx.y * BN;

    const int lane = tid & 63;
    const int wid = tid >> 6;          // 0..3
    const int wr = wid >> 1;           // 0..1 (M)
    const int wc = wid & 1;            // 0..1 (N)
    const int lrow = lane & 15;
    const int kgrp = lane >> 4;        // 0..3

    f32x4 acc[4][2];
    #pragma unroll
    for (int m = 0; m < 4; m++)
        #pragma unroll
        for (int n = 0; n < 2; n++) acc[m][n] = (f32x4){0.f, 0.f, 0.f, 0.f};

    for (int k0 = 0; k0 < 320; k0 += BK) {
        // ---- stage A: 128x32 fp32 -> bf16, 1024 quads, 4 per thread
        #pragma unroll
        for (int i = 0; i < 4; ++i) {
            int q = tid + i * 256;
            int r = q >> 3;
            int c = (q & 7) << 2;
            int gr = bm + r, gk = k0 + c;
            float v0 = 0.f, v1 = 0.f, v2 = 0.f, v3 = 0.f;
            if (gr < n_rows) {
                const float* p = X + (long)gr * H + gk;
                if (gk + 3 < H) {
                    float4 f = *(const float4*)p;
                    v0 = f.x; v1 = f.y; v2 = f.z; v3 = f.w;
                } else {
                    if (gk + 0 < H) v0 = p[0];
                    if (gk + 1 < H) v1 = p[1];
                    if (gk + 2 < H) v2 = p[2];
                }
            }
            short4v h;
            h[0] = (short)f2b(v0); h[1] = (short)f2b(v1);
            h[2] = (short)f2b(v2); h[3] = (short)f2b(v3);
            *(short4v*)&As[r * LDP + c] = h;
        }
        // ---- stage B: 64x32, 512 quads, 2 per thread
        #pragma unroll
        for (int i = 0; i < 2; ++i) {
            int q = tid + i * 256;
            int r = q >> 3;
            int c = (q & 7) << 2;
            int gn = bn + r, gk = k0 + c;
            float v0 = 0.f, v1 = 0.f, v2 = 0.f, v3 = 0.f;
            if (gn < H) {
                const float* p = W + (long)gn * H + gk;
                if (gk + 3 < H) {
                    float4 f = *(const float4*)p;
                    v0 = f.x; v1 = f.y; v2 = f.z; v3 = f.w;
                } else {
                    if (gk + 0 < H) v0 = p[0];
                    if (gk + 1 < H) v1 = p[1];
                    if (gk + 2 < H) v2 = p[2];
                }
            }
            short4v h;
            h[0] = (short)f2b(v0); h[1] = (short)f2b(v1);
            h[2] = (short)f2b(v2); h[3] = (short)f2b(v3);
            *(short4v*)&Bs[r * LDP + c] = h;
        }
        __syncthreads();

        // ---- fragments + MFMA
        bf16x8 af[4], bfr[2];
        #pragma unroll
        for (int m = 0; m < 4; m++) {
            int row = wr * 64 + m * 16 + lrow;
            af[m] = *(const bf16x8*)&As[row * LDP + kgrp * 8];
        }
        #pragma unroll
        for (int n = 0; n < 2; n++) {
            int col = wc * 32 + n * 16 + lrow;
            bfr[n] = *(const bf16x8*)&Bs[col * LDP + kgrp * 8];
        }
        #pragma unroll
        for (int m = 0; m < 4; m++)
            #pragma unroll
            for (int n = 0; n < 2; n++)
                acc[m][n] = __builtin_amdgcn_mfma_f32_16x16x32_bf16(af[m], bfr[n], acc[m][n], 0, 0, 0);
        __syncthreads();
    }

    // ---- epilogue: D layout col=lane&15, row=(lane>>4)*4+reg
    #pragma unroll
    for (int m = 0; m < 4; m++) {
        #pragma unroll
        for (int n = 0; n < 2; n++) {
            int gc = bn + wc * 32 + n * 16 + lrow;
            if (gc >= H) continue;
            #pragma unroll
            for (int r = 0; r < 4; r++) {
                int gr = bm + wr * 64 + m * 16 + kgrp * 4 + r;
                if (gr < n_rows) out[(long)gr * H + gc] = acc[m][n][r];
            }
        }
    }
}

// ---------------------------------------------------------------------------
// GCN gather
// ---------------------------------------------------------------------------
__global__ __launch_bounds__(256) void k_gcn_gather(const float* __restrict__ h,
                                                    const float* __restrict__ dinv,
                                                    const int* __restrict__ offsets,
                                                    const int* __restrict__ csr_src,
                                                    float* __restrict__ out) {
    int i = blockIdx.x;
    int t = threadIdx.x;
    int start = offsets[i], end = offsets[i + 1];
    float di = dinv[i];
    float acc0 = 0.f, acc1 = 0.f;
    __shared__ float wsh[256];
    __shared__ int ssh[256];
    for (int cbase = start; cbase < end; cbase += 256) {
        int p = cbase + t;
        if (p < end) {
            int j = csr_src[p];
            ssh[t] = j;
            wsh[t] = di * dinv[j];
        }
        __syncthreads();
        int cnt = min(256, end - cbase);
        for (int q = 0; q < cnt; q++) {
            float w = wsh[q];
            const float* row = h + (long)ssh[q] * H;
            acc0 += w * row[t];
            if (t + 256 < H) acc1 += w * row[t + 256];
        }
        __syncthreads();
    }
    float* orow = out + (long)i * H;
    orow[t] = fmaxf(acc0, 0.f);
    if (t + 256 < H) orow[t + 256] = fmaxf(acc1, 0.f);
}

// ---------------------------------------------------------------------------
// dual dot
// ---------------------------------------------------------------------------
__global__ void k_dual_dot(const float* __restrict__ x, long x_stride,
                           const float* __restrict__ ai, const float* __restrict__ aj,
                           float* __restrict__ s_i, float* __restrict__ s_j, int n) {
    int wave = blockIdx.x * (blockDim.x / WAVE) + (threadIdx.x >> 6);
    int lane = threadIdx.x & 63;
    if (wave >= n) return;
    const float* row = x + (long)wave * x_stride;
    float d0 = 0.f, d1 = 0.f;
    for (int j = lane; j < H; j += WAVE) {
        float v = row[j];
        d0 += v * ai[j];
        d1 += v * aj[j];
    }
    for (int o = 32; o > 0; o >>= 1) { d0 += __shfl_down(d0, o); d1 += __shfl_down(d1, o); }
    if (lane == 0) { s_i[wave] = d0; s_j[wave] = d1; }
}

// ---------------------------------------------------------------------------
// GAT gather with fused segment softmax
// ---------------------------------------------------------------------------
__global__ __launch_bounds__(256) void k_gat_gather(const float* __restrict__ x, long x_stride,
                                                    const float* __restrict__ s_i_arr,
                                                    const float* __restrict__ s_j_arr,
                                                    const int* __restrict__ offsets,
                                                    const int* __restrict__ csr_src,
                                                    float* __restrict__ out, long out_stride,
                                                    int out_off) {
    int i = blockIdx.x;
    int t = threadIdx.x;
    int start = offsets[i], end = offsets[i + 1];
    float acc0 = 0.f, acc1 = 0.f;
    __shared__ float red[256];
    __shared__ float wsh[256];
    __shared__ int ssh[256];
    if (start < end) {
        float si = s_i_arr[i];
        float lm = -1e30f;
        for (int p = start + t; p < end; p += 256) {
            float sc = si + s_j_arr[csr_src[p]];
            sc = (sc >= 0.f) ? sc : 0.01f * sc;
            lm = fmaxf(lm, sc);
        }
        red[t] = lm;
        __syncthreads();
        for (int o = 128; o > 0; o >>= 1) {
            if (t < o) red[t] = fmaxf(red[t], red[t + o]);
            __syncthreads();
        }
        float m = red[0];
        __syncthreads();
        float ls = 0.f;
        for (int p = start + t; p < end; p += 256) {
            float sc = si + s_j_arr[csr_src[p]];
            sc = (sc >= 0.f) ? sc : 0.01f * sc;
            ls += expf(sc - m);
        }
        red[t] = ls;
        __syncthreads();
        for (int o = 128; o > 0; o >>= 1) {
            if (t < o) red[t] += red[t + o];
            __syncthreads();
        }
        float inv_denom = 1.0f / (red[0] + 1e-16f);
        __syncthreads();
        for (int cbase = start; cbase < end; cbase += 256) {
            int p = cbase + t;
            if (p < end) {
                int j = csr_src[p];
                float sc = si + s_j_arr[j];
                sc = (sc >= 0.f) ? sc : 0.01f * sc;
                ssh[t] = j;
                wsh[t] = expf(sc - m) * inv_denom;
            }
            __syncthreads();
            int cnt = min(256, end - cbase);
            for (int q = 0; q < cnt; q++) {
                float w = wsh[q];
                const float* row = x + (long)ssh[q] * x_stride;
                acc0 += w * row[t];
                if (t + 256 < H) acc1 += w * row[t + 256];
            }
            __syncthreads();
        }
    }
    float* orow = out + (long)i * out_stride + out_off;
    orow[t] = fmaxf(acc0, 0.f);
    if (t + 256 < H) orow[t + 256] = fmaxf(acc1, 0.f);
}

// ---------------------------------------------------------------------------
// highway elementwise
// ---------------------------------------------------------------------------
__global__ void k_highway(const float* __restrict__ pre, const float* __restrict__ b,
                          const float* __restrict__ xnew, const float* __restrict__ xold,
                          float* __restrict__ out, long out_stride, int n_rows) {
    long total = (long)n_rows * H;
    long stride = (long)gridDim.x * blockDim.x;
    for (long idx = (long)blockIdx.x * blockDim.x + threadIdx.x; idx < total; idx += stride) {
        long row = idx / H;
        int col = (int)(idx - row * H);
        float g = 1.0f / (1.0f + expf(-(pre[idx] + b[col])));
        out[row * out_stride + col] = g * xnew[idx] + (1.0f - g) * xold[idx];
    }
}

// ---------------------------------------------------------------------------
// launch
// ---------------------------------------------------------------------------
extern "C" void kernel_launch(void* const* d_in, const int* in_sizes, int n_in,
                              void* d_out, int out_size, void* d_ws, size_t ws_size,
                              hipStream_t stream) {
    const float* x_e     = (const float*)d_in[0];
    const int*   ei_all  = (const int*)d_in[3];
    const float* gcn1_W  = (const float*)d_in[5];
    const float* hw1_W   = (const float*)d_in[6];
    const float* hw1_b   = (const float*)d_in[7];
    const float* gat1_ai = (const float*)d_in[8];
    const float* gat1_aj = (const float*)d_in[9];
    const float* ghw1_W  = (const float*)d_in[10];
    const float* ghw1_b  = (const float*)d_in[11];
    const float* gat2_ai = (const float*)d_in[12];
    const float* gat2_aj = (const float*)d_in[13];
    const float* ghw2_W  = (const float*)d_in[14];
    const float* ghw2_b  = (const float*)d_in[15];
    const float* gat_ai  = (const float*)d_in[16];
    const float* gat_aj  = (const float*)d_in[17];

    const int N = in_sizes[0] / H;
    const int E = in_sizes[3] / 2;
    const int* ei_j = ei_all;
    const int* ei_i = ei_all + E;

    float* out = (float*)d_out;

    size_t NH = (size_t)N * H;
    float* A      = (float*)d_ws;
    float* B      = A + NH;
    float* C      = B + NH;
    float* sbi    = C + NH;
    float* sbj    = sbi + N;
    float* dinv   = sbj + N;
    int*   deg    = (int*)(dinv + N);
    int*   offs   = deg + N;
    int*   cursor = offs + (N + 1);
    int*   csr    = cursor + N;

    dim3 blk256(256);
    int rowsPerBlock = 256 / WAVE;
    dim3 gridRows((N + rowsPerBlock - 1) / rowsPerBlock);
    dim3 gridNode(N);
    dim3 gridE(2048);
    dim3 gridEW(2048);
    dim3 gridGemm((N + BM - 1) / BM, (H + BN - 1) / BN);

    // 1. x0 = l2_normalize(x_e) -> A
    hipLaunchKernelGGL(k_l2norm, gridRows, blk256, 0, stream, x_e, A, N);

    // 2. CSR build
    hipLaunchKernelGGL(k_zero_int, dim3(256), blk256, 0, stream, deg, N);
    hipLaunchKernelGGL(k_count_deg, gridE, blk256, 0, stream, ei_i, deg, E);
    hipLaunchKernelGGL(k_dinv, dim3(256), blk256, 0, stream, deg, dinv, N);
    hipLaunchKernelGGL(k_scan, dim3(1), dim3(1024), 0, stream, deg, offs, cursor, N);
    hipLaunchKernelGGL(k_fill_csr, gridE, blk256, 0, stream, ei_j, ei_i, cursor, csr, E);

    // 3. h = x0 @ gcn1_W.T -> B
    hipLaunchKernelGGL(k_gemm_bf16, gridGemm, blk256, 0, stream, A, gcn1_W, B, N);

    // 4. gcn_out -> C
    hipLaunchKernelGGL(k_gcn_gather, gridNode, blk256, 0, stream, B, dinv, offs, csr, C);

    // 5. gate-pre = x0 @ hw1_W.T -> B ; x2 = hw(x0, gcn_out) -> C
    hipLaunchKernelGGL(k_gemm_bf16, gridGemm, blk256, 0, stream, A, hw1_W, B, N);
    hipLaunchKernelGGL(k_highway, gridEW, blk256, 0, stream, B, hw1_b, C, A, C, (long)H, N);

    // 6. GAT1: input C (x2) -> B
    hipLaunchKernelGGL(k_dual_dot, gridRows, blk256, 0, stream, C, (long)H, gat1_ai, gat1_aj, sbi, sbj, N);
    hipLaunchKernelGGL(k_gat_gather, gridNode, blk256, 0, stream, C, (long)H, sbi, sbj, offs, csr, B, (long)H, 0);

    // 7. gate-pre = x2 @ ghw1_W.T -> A ; x3 = hw(x2, gat1_out) -> A
    hipLaunchKernelGGL(k_gemm_bf16, gridGemm, blk256, 0, stream, C, ghw1_W, A, N);
    hipLaunchKernelGGL(k_highway, gridEW, blk256, 0, stream, A, ghw1_b, B, C, A, (long)H, N);

    // 8. GAT2: input A (x3) -> B
    hipLaunchKernelGGL(k_dual_dot, gridRows, blk256, 0, stream, A, (long)H, gat2_ai, gat2_aj, sbi, sbj, N);
    hipLaunchKernelGGL(k_gat_gather, gridNode, blk256, 0, stream, A, (long)H, sbi, sbj, offs, csr, B, (long)H, 0);

    // 9. gate-pre = x2 @ ghw2_W.T -> A ; xe = hw(x2, gat2_out) -> d_out[:, 0:300]
    hipLaunchKernelGGL(k_gemm_bf16, gridGemm, blk256, 0, stream, C, ghw2_W, A, N);
    hipLaunchKernelGGL(k_highway, gridEW, blk256, 0, stream, A, ghw2_b, B, C, out, (long)(2 * H), N);

    // 10. final GAT on xe (stride 600) -> d_out[:, 300:600]
    hipLaunchKernelGGL(k_dual_dot, gridRows, blk256, 0, stream, out, (long)(2 * H), gat_ai, gat_aj, sbi, sbj, N);
    hipLaunchKernelGGL(k_gat_gather, gridNode, blk256, 0, stream, out, (long)(2 * H), sbi, sbj, offs, csr, out, (long)(2 * H), H);
}

// Round 4
// 1288.199 us; speedup vs baseline: 1.7790x; 1.3424x over previous
//
#include <hip/hip_runtime.h>
#include <hip/hip_bf16.h>
#include <math.h>

#define H 300
#define WAVE 64
#define STRB 304   // padded bf16 row stride (608 B, 16B-aligned)

typedef short bf16x8 __attribute__((ext_vector_type(8)));
typedef unsigned short u16;
typedef u16 u16x8 __attribute__((ext_vector_type(8)));
typedef short short4v __attribute__((ext_vector_type(4)));
typedef float f32x4 __attribute__((ext_vector_type(4)));

__device__ inline unsigned short f2b(float f) {
    union { float f; unsigned int u; } x; x.f = f;
    unsigned int r = x.u + 0x7FFF + ((x.u >> 16) & 1);
    return (unsigned short)(r >> 16);
}
__device__ inline float b2f(u16 h) {
    union { float f; unsigned int u; } x; x.u = ((unsigned int)h) << 16;
    return x.f;
}

// ---------------------------------------------------------------------------
__global__ void k_l2norm(const float* __restrict__ x, float* __restrict__ out, int n) {
    int wave = blockIdx.x * (blockDim.x / WAVE) + (threadIdx.x >> 6);
    int lane = threadIdx.x & 63;
    if (wave >= n) return;
    const float* row = x + (long)wave * H;
    float s = 0.f;
    for (int j = lane; j < H; j += WAVE) { float v = row[j]; s += v * v; }
    for (int o = 32; o > 0; o >>= 1) s += __shfl_xor(s, o);
    float sc = 1.0f / fmaxf(sqrtf(s), 1e-12f);
    float* orow = out + (long)wave * H;
    for (int j = lane; j < H; j += WAVE) orow[j] = row[j] * sc;
}

__global__ void k_zero_int(int* p, int n) {
    int i = blockIdx.x * blockDim.x + threadIdx.x;
    int stride = gridDim.x * blockDim.x;
    for (; i < n; i += stride) p[i] = 0;
}

__global__ void k_count_deg(const int* __restrict__ ei_i, int* __restrict__ deg, int E) {
    int i = blockIdx.x * blockDim.x + threadIdx.x;
    int stride = gridDim.x * blockDim.x;
    for (; i < E; i += stride) atomicAdd(&deg[ei_i[i]], 1);
}

__global__ void k_dinv(const int* __restrict__ deg, float* __restrict__ dinv, int n) {
    int i = blockIdx.x * blockDim.x + threadIdx.x;
    int stride = gridDim.x * blockDim.x;
    for (; i < n; i += stride) {
        int d = deg[i];
        dinv[i] = (d > 0) ? 1.0f / sqrtf((float)d) : 0.0f;
    }
}

__global__ void k_scan(const int* __restrict__ deg, int* __restrict__ offsets,
                       int* __restrict__ cursor, int n) {
    __shared__ int sh[1024];
    __shared__ int carry_sh;
    int tid = threadIdx.x;
    if (tid == 0) carry_sh = 0;
    __syncthreads();
    for (int base = 0; base < n; base += 1024) {
        int v = (base + tid < n) ? deg[base + tid] : 0;
        sh[tid] = v;
        __syncthreads();
        for (int off = 1; off < 1024; off <<= 1) {
            int add = (tid >= off) ? sh[tid - off] : 0;
            __syncthreads();
            sh[tid] += add;
            __syncthreads();
        }
        int total = sh[1023];
        int exc = sh[tid] - v;
        int carry = carry_sh;
        if (base + tid < n) {
            int o = carry + exc;
            offsets[base + tid] = o;
            cursor[base + tid] = o;
        }
        __syncthreads();
        if (tid == 0) carry_sh = carry + total;
        __syncthreads();
    }
    if (tid == 0) offsets[n] = carry_sh;
}

__global__ void k_fill_csr(const int* __restrict__ ei_j, const int* __restrict__ ei_i,
                           int* __restrict__ cursor, int* __restrict__ csr_src, int E) {
    int i = blockIdx.x * blockDim.x + threadIdx.x;
    int stride = gridDim.x * blockDim.x;
    for (; i < E; i += stride) {
        int dst = ei_i[i];
        int pos = atomicAdd(&cursor[dst], 1);
        csr_src[pos] = ei_j[i];
    }
}

// ---------------------------------------------------------------------------
// bf16 MFMA NT GEMM; out_bf16 ? writes ushort rows (stride STRB, pads zeroed)
//                             : writes fp32 rows (stride H)
// ---------------------------------------------------------------------------
#define BM 128
#define BN 64
#define BK 32
#define LDP 40

__global__ __launch_bounds__(256) void k_gemm_bf16(const float* __restrict__ X,
                                                   const float* __restrict__ W,
                                                   void* __restrict__ outp, int out_bf16,
                                                   int n_rows) {
    __shared__ __align__(16) short As[BM * LDP];
    __shared__ __align__(16) short Bs[BN * LDP];
    const int tid = threadIdx.x;
    const int bm = blockIdx.x * BM;
    const int bn = blockIdx.y * BN;
    const int lane = tid & 63;
    const int wid = tid >> 6;
    const int wr = wid >> 1;
    const int wc = wid & 1;
    const int lrow = lane & 15;
    const int kgrp = lane >> 4;

    f32x4 acc[4][2];
    #pragma unroll
    for (int m = 0; m < 4; m++)
        #pragma unroll
        for (int n = 0; n < 2; n++) acc[m][n] = (f32x4){0.f, 0.f, 0.f, 0.f};

    for (int k0 = 0; k0 < 320; k0 += BK) {
        #pragma unroll
        for (int i = 0; i < 4; ++i) {
            int q = tid + i * 256;
            int r = q >> 3;
            int c = (q & 7) << 2;
            int gr = bm + r, gk = k0 + c;
            float v0 = 0.f, v1 = 0.f, v2 = 0.f, v3 = 0.f;
            if (gr < n_rows) {
                const float* p = X + (long)gr * H + gk;
                if (gk + 3 < H) {
                    float4 f = *(const float4*)p;
                    v0 = f.x; v1 = f.y; v2 = f.z; v3 = f.w;
                } else {
                    if (gk + 0 < H) v0 = p[0];
                    if (gk + 1 < H) v1 = p[1];
                    if (gk + 2 < H) v2 = p[2];
                }
            }
            short4v h;
            h[0] = (short)f2b(v0); h[1] = (short)f2b(v1);
            h[2] = (short)f2b(v2); h[3] = (short)f2b(v3);
            *(short4v*)&As[r * LDP + c] = h;
        }
        #pragma unroll
        for (int i = 0; i < 2; ++i) {
            int q = tid + i * 256;
            int r = q >> 3;
            int c = (q & 7) << 2;
            int gn = bn + r, gk = k0 + c;
            float v0 = 0.f, v1 = 0.f, v2 = 0.f, v3 = 0.f;
            if (gn < H) {
                const float* p = W + (long)gn * H + gk;
                if (gk + 3 < H) {
                    float4 f = *(const float4*)p;
                    v0 = f.x; v1 = f.y; v2 = f.z; v3 = f.w;
                } else {
                    if (gk + 0 < H) v0 = p[0];
                    if (gk + 1 < H) v1 = p[1];
                    if (gk + 2 < H) v2 = p[2];
                }
            }
            short4v h;
            h[0] = (short)f2b(v0); h[1] = (short)f2b(v1);
            h[2] = (short)f2b(v2); h[3] = (short)f2b(v3);
            *(short4v*)&Bs[r * LDP + c] = h;
        }
        __syncthreads();

        bf16x8 af[4], bfr[2];
        #pragma unroll
        for (int m = 0; m < 4; m++) {
            int row = wr * 64 + m * 16 + lrow;
            af[m] = *(const bf16x8*)&As[row * LDP + kgrp * 8];
        }
        #pragma unroll
        for (int n = 0; n < 2; n++) {
            int col = wc * 32 + n * 16 + lrow;
            bfr[n] = *(const bf16x8*)&Bs[col * LDP + kgrp * 8];
        }
        #pragma unroll
        for (int m = 0; m < 4; m++)
            #pragma unroll
            for (int n = 0; n < 2; n++)
                acc[m][n] = __builtin_amdgcn_mfma_f32_16x16x32_bf16(af[m], bfr[n], acc[m][n], 0, 0, 0);
        __syncthreads();
    }

    if (!out_bf16) {
        float* out = (float*)outp;
        #pragma unroll
        for (int m = 0; m < 4; m++)
            #pragma unroll
            for (int n = 0; n < 2; n++) {
                int gc = bn + wc * 32 + n * 16 + lrow;
                if (gc >= H) continue;
                #pragma unroll
                for (int r = 0; r < 4; r++) {
                    int gr = bm + wr * 64 + m * 16 + kgrp * 4 + r;
                    if (gr < n_rows) out[(long)gr * H + gc] = acc[m][n][r];
                }
            }
    } else {
        u16* out = (u16*)outp;
        #pragma unroll
        for (int m = 0; m < 4; m++)
            #pragma unroll
            for (int n = 0; n < 2; n++) {
                int gc = bn + wc * 32 + n * 16 + lrow;
                if (gc >= STRB) continue;
                #pragma unroll
                for (int r = 0; r < 4; r++) {
                    int gr = bm + wr * 64 + m * 16 + kgrp * 4 + r;
                    if (gr < n_rows) out[(long)gr * STRB + gc] = (gc < H) ? f2b(acc[m][n][r]) : 0;
                }
            }
    }
}

// ---------------------------------------------------------------------------
// GCN gather from bf16 rows
// ---------------------------------------------------------------------------
__global__ __launch_bounds__(256) void k_gcn_gather_b(const u16* __restrict__ xb,
                                                      const float* __restrict__ dinv,
                                                      const int* __restrict__ offs,
                                                      const int* __restrict__ csr,
                                                      float* __restrict__ out) {
    int i = blockIdx.x;
    int t = threadIdx.x;
    int lane = t & 63, wid = t >> 6;
    int start = offs[i], end = offs[i + 1];
    __shared__ float wsh[256];
    __shared__ int ssh[256];
    __shared__ float redbuf[4 * STRB];
    float accv[8] = {0.f, 0.f, 0.f, 0.f, 0.f, 0.f, 0.f, 0.f};
    float di = dinv[i];
    for (int cbase = start; cbase < end; cbase += 256) {
        int p = cbase + t;
        if (p < end) {
            int src = csr[p];
            ssh[t] = src;
            wsh[t] = di * dinv[src];
        }
        __syncthreads();
        int cnt = min(256, end - cbase);
        for (int q = wid; q < cnt; q += 4) {
            float w = wsh[q];
            const u16* row = xb + (long)ssh[q] * STRB;
            if (lane < 38) {
                u16x8 v = *(const u16x8*)&row[lane * 8];
                #pragma unroll
                for (int j = 0; j < 8; j++) accv[j] += w * b2f(v[j]);
            }
        }
        __syncthreads();
    }
    if (lane < 38) {
        #pragma unroll
        for (int j = 0; j < 8; j++) redbuf[wid * STRB + lane * 8 + j] = accv[j];
    }
    __syncthreads();
    for (int c = t; c < H; c += 256) {
        float s = redbuf[c] + redbuf[STRB + c] + redbuf[2 * STRB + c] + redbuf[3 * STRB + c];
        out[(long)i * H + c] = fmaxf(s, 0.f);
    }
}

// ---------------------------------------------------------------------------
// dual dot
// ---------------------------------------------------------------------------
__global__ void k_dual_dot(const float* __restrict__ x, long x_stride,
                           const float* __restrict__ ai, const float* __restrict__ aj,
                           float* __restrict__ s_i, float* __restrict__ s_j, int n) {
    int wave = blockIdx.x * (blockDim.x / WAVE) + (threadIdx.x >> 6);
    int lane = threadIdx.x & 63;
    if (wave >= n) return;
    const float* row = x + (long)wave * x_stride;
    float d0 = 0.f, d1 = 0.f;
    for (int j = lane; j < H; j += WAVE) {
        float v = row[j];
        d0 += v * ai[j];
        d1 += v * aj[j];
    }
    for (int o = 32; o > 0; o >>= 1) { d0 += __shfl_down(d0, o); d1 += __shfl_down(d1, o); }
    if (lane == 0) { s_i[wave] = d0; s_j[wave] = d1; }
}

// ---------------------------------------------------------------------------
// GAT gather from bf16 rows with fused segment-softmax
// ---------------------------------------------------------------------------
__global__ __launch_bounds__(256) void k_gat_gather_b(const u16* __restrict__ xb,
                                                      const float* __restrict__ s_i_arr,
                                                      const float* __restrict__ s_j_arr,
                                                      const int* __restrict__ offs,
                                                      const int* __restrict__ csr,
                                                      float* __restrict__ out, long out_stride,
                                                      int out_off) {
    int i = blockIdx.x;
    int t = threadIdx.x;
    int lane = t & 63, wid = t >> 6;
    int start = offs[i], end = offs[i + 1];
    int deg = end - start;
    __shared__ float wsh[256];
    __shared__ int ssh[256];
    __shared__ float redm[256];
    __shared__ float reds[256];
    __shared__ float redbuf[4 * STRB];
    float accv[8] = {0.f, 0.f, 0.f, 0.f, 0.f, 0.f, 0.f, 0.f};

    if (deg > 0) {
        float si = s_i_arr[i];
        if (deg <= 256) {
            // fast path: stage scores once, no csr re-read
            float sc = 0.f;
            float m_t = -1e30f, s_t = 0.f;
            if (t < deg) {
                int src = csr[start + t];
                sc = si + s_j_arr[src];
                sc = (sc >= 0.f) ? sc : 0.01f * sc;
                m_t = sc; s_t = 1.0f;
                ssh[t] = src;
            }
            redm[t] = m_t; reds[t] = s_t;
            __syncthreads();
            for (int o = 128; o > 0; o >>= 1) {
                if (t < o) {
                    float m1 = redm[t], m2 = redm[t + o];
                    float mm = fmaxf(m1, m2);
                    reds[t] = reds[t] * expf(m1 - mm) + reds[t + o] * expf(m2 - mm);
                    redm[t] = mm;
                }
                __syncthreads();
            }
            float m = redm[0];
            float inv = 1.0f / (reds[0] + 1e-16f);
            if (t < deg) wsh[t] = expf(sc - m) * inv;
            __syncthreads();
            for (int q = wid; q < deg; q += 4) {
                float w = wsh[q];
                const u16* row = xb + (long)ssh[q] * STRB;
                if (lane < 38) {
                    u16x8 v = *(const u16x8*)&row[lane * 8];
                    #pragma unroll
                    for (int j = 0; j < 8; j++) accv[j] += w * b2f(v[j]);
                }
            }
        } else {
            // general path: online max/denom pass, then chunked gather
            float m_t = -1e30f, s_t = 0.f;
            for (int p = start + t; p < end; p += 256) {
                float sc = si + s_j_arr[csr[p]];
                sc = (sc >= 0.f) ? sc : 0.01f * sc;
                if (sc > m_t) { s_t = s_t * expf(m_t - sc) + 1.0f; m_t = sc; }
                else s_t += expf(sc - m_t);
            }
            redm[t] = m_t; reds[t] = s_t;
            __syncthreads();
            for (int o = 128; o > 0; o >>= 1) {
                if (t < o) {
                    float m1 = redm[t], m2 = redm[t + o];
                    float mm = fmaxf(m1, m2);
                    reds[t] = reds[t] * expf(m1 - mm) + reds[t + o] * expf(m2 - mm);
                    redm[t] = mm;
                }
                __syncthreads();
            }
            float m = redm[0];
            float inv = 1.0f / (reds[0] + 1e-16f);
            __syncthreads();
            for (int cbase = start; cbase < end; cbase += 256) {
                int p = cbase + t;
                if (p < end) {
                    int src = csr[p];
                    float sc = si + s_j_arr[src];
                    sc = (sc >= 0.f) ? sc : 0.01f * sc;
                    ssh[t] = src;
                    wsh[t] = expf(sc - m) * inv;
                }
                __syncthreads();
                int cnt = min(256, end - cbase);
                for (int q = wid; q < cnt; q += 4) {
                    float w = wsh[q];
                    const u16* row = xb + (long)ssh[q] * STRB;
                    if (lane < 38) {
                        u16x8 v = *(const u16x8*)&row[lane * 8];
                        #pragma unroll
                        for (int j = 0; j < 8; j++) accv[j] += w * b2f(v[j]);
                    }
                }
                __syncthreads();
            }
        }
    }
    if (lane < 38) {
        #pragma unroll
        for (int j = 0; j < 8; j++) redbuf[wid * STRB + lane * 8 + j] = accv[j];
    }
    __syncthreads();
    for (int c = t; c < H; c += 256) {
        float s = redbuf[c] + redbuf[STRB + c] + redbuf[2 * STRB + c] + redbuf[3 * STRB + c];
        out[(long)i * out_stride + out_off + c] = fmaxf(s, 0.f);
    }
}

// ---------------------------------------------------------------------------
// highway elementwise, optional bf16 mirror (stride STRB, pads zeroed)
// ---------------------------------------------------------------------------
__global__ void k_highway(const float* __restrict__ pre, const float* __restrict__ b,
                          const float* __restrict__ xnew, const float* __restrict__ xold,
                          float* __restrict__ out, long out_stride,
                          u16* __restrict__ mirror, int n_rows) {
    long total = (long)n_rows * H;
    long stride = (long)gridDim.x * blockDim.x;
    for (long idx = (long)blockIdx.x * blockDim.x + threadIdx.x; idx < total; idx += stride) {
        long row = idx / H;
        int col = (int)(idx - row * H);
        float g = 1.0f / (1.0f + expf(-(pre[idx] + b[col])));
        float val = g * xnew[idx] + (1.0f - g) * xold[idx];
        out[row * out_stride + col] = val;
        if (mirror) {
            mirror[row * STRB + col] = f2b(val);
            if (col < STRB - H) mirror[row * STRB + H + col] = 0;
        }
    }
}

// ---------------------------------------------------------------------------
// strided fp32 -> padded bf16 conversion
// ---------------------------------------------------------------------------
__global__ void k_conv_b(const float* __restrict__ src, long sstride,
                         u16* __restrict__ dst, int n_rows) {
    long total = (long)n_rows * STRB;
    long stride = (long)gridDim.x * blockDim.x;
    for (long idx = (long)blockIdx.x * blockDim.x + threadIdx.x; idx < total; idx += stride) {
        long row = idx / STRB;
        int col = (int)(idx - row * STRB);
        dst[idx] = (col < H) ? f2b(src[row * sstride + col]) : 0;
    }
}

// ---------------------------------------------------------------------------
// launch
// ---------------------------------------------------------------------------
extern "C" void kernel_launch(void* const* d_in, const int* in_sizes, int n_in,
                              void* d_out, int out_size, void* d_ws, size_t ws_size,
                              hipStream_t stream) {
    const float* x_e     = (const float*)d_in[0];
    const int*   ei_all  = (const int*)d_in[3];
    const float* gcn1_W  = (const float*)d_in[5];
    const float* hw1_W   = (const float*)d_in[6];
    const float* hw1_b   = (const float*)d_in[7];
    const float* gat1_ai = (const float*)d_in[8];
    const float* gat1_aj = (const float*)d_in[9];
    const float* ghw1_W  = (const float*)d_in[10];
    const float* ghw1_b  = (const float*)d_in[11];
    const float* gat2_ai = (const float*)d_in[12];
    const float* gat2_aj = (const float*)d_in[13];
    const float* ghw2_W  = (const float*)d_in[14];
    const float* ghw2_b  = (const float*)d_in[15];
    const float* gat_ai  = (const float*)d_in[16];
    const float* gat_aj  = (const float*)d_in[17];

    const int N = in_sizes[0] / H;
    const int E = in_sizes[3] / 2;
    const int* ei_j = ei_all;
    const int* ei_i = ei_all + E;

    float* out = (float*)d_out;

    size_t NH = (size_t)N * H;
    float* A      = (float*)d_ws;
    float* B      = A + NH;
    float* C      = B + NH;
    float* sbi    = C + NH;
    float* sbj    = sbi + N;
    float* dinv   = sbj + N;
    int*   deg    = (int*)(dinv + N);
    int*   offs   = deg + N;
    int*   cursor = offs + (N + 1);
    int*   csr    = cursor + N;

    // bf16 mirrors in dead buffers
    u16* hb  = (u16*)B;      // GCN h, steps 3-4
    u16* xmb = (u16*)d_out;  // x2b (steps 5-6) then x3b (steps 7-8)
    u16* xeb = (u16*)B;      // xe, steps 9.5-10

    dim3 blk256(256);
    int rowsPerBlock = 256 / WAVE;
    dim3 gridRows((N + rowsPerBlock - 1) / rowsPerBlock);
    dim3 gridNode(N);
    dim3 gridE(2048);
    dim3 gridEW(2048);
    dim3 gridGemm((N + BM - 1) / BM, (H + BN - 1) / BN);

    // 1. x0 = l2_normalize(x_e) -> A
    hipLaunchKernelGGL(k_l2norm, gridRows, blk256, 0, stream, x_e, A, N);

    // 2. CSR build
    hipLaunchKernelGGL(k_zero_int, dim3(256), blk256, 0, stream, deg, N);
    hipLaunchKernelGGL(k_count_deg, gridE, blk256, 0, stream, ei_i, deg, E);
    hipLaunchKernelGGL(k_dinv, dim3(256), blk256, 0, stream, deg, dinv, N);
    hipLaunchKernelGGL(k_scan, dim3(1), dim3(1024), 0, stream, deg, offs, cursor, N);
    hipLaunchKernelGGL(k_fill_csr, gridE, blk256, 0, stream, ei_j, ei_i, cursor, csr, E);

    // 3. hb = bf16(x0 @ gcn1_W.T) -> B (bf16, stride STRB)
    hipLaunchKernelGGL(k_gemm_bf16, gridGemm, blk256, 0, stream, A, gcn1_W, (void*)hb, 1, N);

    // 4. gcn_out -> C
    hipLaunchKernelGGL(k_gcn_gather_b, gridNode, blk256, 0, stream, hb, dinv, offs, csr, C);

    // 5. pre = x0 @ hw1_W.T -> B ; x2 = hw(x0, gcn_out) -> C (+ mirror x2b)
    hipLaunchKernelGGL(k_gemm_bf16, gridGemm, blk256, 0, stream, A, hw1_W, (void*)B, 0, N);
    hipLaunchKernelGGL(k_highway, gridEW, blk256, 0, stream, B, hw1_b, C, A, C, (long)H, xmb, N);

    // 6. GAT1 on x2 -> B
    hipLaunchKernelGGL(k_dual_dot, gridRows, blk256, 0, stream, C, (long)H, gat1_ai, gat1_aj, sbi, sbj, N);
    hipLaunchKernelGGL(k_gat_gather_b, gridNode, blk256, 0, stream, xmb, sbi, sbj, offs, csr, B, (long)H, 0);

    // 7. pre = x2 @ ghw1_W.T -> A ; x3 = hw(x2, gat1_out) -> A (+ mirror x3b)
    hipLaunchKernelGGL(k_gemm_bf16, gridGemm, blk256, 0, stream, C, ghw1_W, (void*)A, 0, N);
    hipLaunchKernelGGL(k_highway, gridEW, blk256, 0, stream, A, ghw1_b, B, C, A, (long)H, xmb, N);

    // 8. GAT2 on x3 -> B
    hipLaunchKernelGGL(k_dual_dot, gridRows, blk256, 0, stream, A, (long)H, gat2_ai, gat2_aj, sbi, sbj, N);
    hipLaunchKernelGGL(k_gat_gather_b, gridNode, blk256, 0, stream, xmb, sbi, sbj, offs, csr, B, (long)H, 0);

    // 9. pre = x2 @ ghw2_W.T -> A ; xe = hw(x2, gat2_out) -> d_out[:,0:300]
    hipLaunchKernelGGL(k_gemm_bf16, gridGemm, blk256, 0, stream, C, ghw2_W, (void*)A, 0, N);
    hipLaunchKernelGGL(k_highway, gridEW, blk256, 0, stream, A, ghw2_b, B, C, out, (long)(2 * H), (u16*)nullptr, N);

    // 9.5 xeb = bf16(xe) -> B
    hipLaunchKernelGGL(k_conv_b, gridEW, blk256, 0, stream, out, (long)(2 * H), xeb, N);

    // 10. final GAT on xe -> d_out[:,300:600]
    hipLaunchKernelGGL(k_dual_dot, gridRows, blk256, 0, stream, out, (long)(2 * H), gat_ai, gat_aj, sbi, sbj, N);
    hipLaunchKernelGGL(k_gat_gather_b, gridNode, blk256, 0, stream, xeb, sbi, sbj, offs, csr, out, (long)(2 * H), H);
}

// Round 5
// 1038.671 us; speedup vs baseline: 2.2063x; 1.2402x over previous
//
#include <hip/hip_runtime.h>
#include <hip/hip_bf16.h>
#include <math.h>

#define H 300
#define WAVE 64
#define STRB 320   // padded bf16 row stride (640 B; 40 chunks of 16 B)
#define NCH 40     // u16x8 chunks per row
#define NS 6       // edge streams per gather block
#define ACT 240    // NS*NCH active threads

typedef short bf16x8 __attribute__((ext_vector_type(8)));
typedef unsigned short u16;
typedef u16 u16x8 __attribute__((ext_vector_type(8)));
typedef float f32x4 __attribute__((ext_vector_type(4)));

__device__ inline unsigned short f2b(float f) {
    union { float f; unsigned int u; } x; x.f = f;
    unsigned int r = x.u + 0x7FFF + ((x.u >> 16) & 1);
    return (unsigned short)(r >> 16);
}
__device__ inline float b2f(u16 h) {
    union { float f; unsigned int u; } x; x.u = ((unsigned int)h) << 16;
    return x.f;
}

// ---------------------------------------------------------------------------
// l2 normalize rows: one wave per row; writes fp32 + padded bf16 mirror
// ---------------------------------------------------------------------------
__global__ void k_l2norm(const float* __restrict__ x, float* __restrict__ out,
                         u16* __restrict__ outb, int n) {
    int wave = blockIdx.x * (blockDim.x / WAVE) + (threadIdx.x >> 6);
    int lane = threadIdx.x & 63;
    if (wave >= n) return;
    const float* row = x + (long)wave * H;
    float s = 0.f;
    for (int j = lane; j < H; j += WAVE) { float v = row[j]; s += v * v; }
    for (int o = 32; o > 0; o >>= 1) s += __shfl_xor(s, o);
    float sc = 1.0f / fmaxf(sqrtf(s), 1e-12f);
    float* orow = out + (long)wave * H;
    u16* brow = outb + (long)wave * STRB;
    for (int j = lane; j < H; j += WAVE) {
        float v = row[j] * sc;
        orow[j] = v;
        brow[j] = f2b(v);
    }
    for (int j = H + lane; j < STRB; j += WAVE) brow[j] = 0;
}

__global__ void k_zero_int(int* p, int n) {
    int i = blockIdx.x * blockDim.x + threadIdx.x;
    int stride = gridDim.x * blockDim.x;
    for (; i < n; i += stride) p[i] = 0;
}

__global__ void k_count_deg(const int* __restrict__ ei_i, int* __restrict__ deg, int E) {
    int i = blockIdx.x * blockDim.x + threadIdx.x;
    int stride = gridDim.x * blockDim.x;
    for (; i < E; i += stride) atomicAdd(&deg[ei_i[i]], 1);
}

__global__ void k_dinv(const int* __restrict__ deg, float* __restrict__ dinv, int n) {
    int i = blockIdx.x * blockDim.x + threadIdx.x;
    int stride = gridDim.x * blockDim.x;
    for (; i < n; i += stride) {
        int d = deg[i];
        dinv[i] = (d > 0) ? 1.0f / sqrtf((float)d) : 0.0f;
    }
}

__global__ void k_scan(const int* __restrict__ deg, int* __restrict__ offsets,
                       int* __restrict__ cursor, int n) {
    __shared__ int sh[1024];
    __shared__ int carry_sh;
    int tid = threadIdx.x;
    if (tid == 0) carry_sh = 0;
    __syncthreads();
    for (int base = 0; base < n; base += 1024) {
        int v = (base + tid < n) ? deg[base + tid] : 0;
        sh[tid] = v;
        __syncthreads();
        for (int off = 1; off < 1024; off <<= 1) {
            int add = (tid >= off) ? sh[tid - off] : 0;
            __syncthreads();
            sh[tid] += add;
            __syncthreads();
        }
        int total = sh[1023];
        int exc = sh[tid] - v;
        int carry = carry_sh;
        if (base + tid < n) {
            int o = carry + exc;
            offsets[base + tid] = o;
            cursor[base + tid] = o;
        }
        __syncthreads();
        if (tid == 0) carry_sh = carry + total;
        __syncthreads();
    }
    if (tid == 0) offsets[n] = carry_sh;
}

__global__ void k_fill_csr(const int* __restrict__ ei_j, const int* __restrict__ ei_i,
                           int* __restrict__ cursor, int* __restrict__ csr_src, int E) {
    int i = blockIdx.x * blockDim.x + threadIdx.x;
    int stride = gridDim.x * blockDim.x;
    for (; i < E; i += stride) {
        int dst = ei_i[i];
        int pos = atomicAdd(&cursor[dst], 1);
        csr_src[pos] = ei_j[i];
    }
}

// ---------------------------------------------------------------------------
// W fp32 [300][300] -> padded bf16 [320][320], pads zero
// ---------------------------------------------------------------------------
__global__ void k_conv_w(const float* __restrict__ W, u16* __restrict__ Wb) {
    int idx = blockIdx.x * blockDim.x + threadIdx.x;
    int stride = gridDim.x * blockDim.x;
    for (; idx < STRB * STRB; idx += stride) {
        int r = idx / STRB, c = idx - r * STRB;
        Wb[idx] = (r < H && c < H) ? f2b(W[r * H + c]) : 0;
    }
}

// ---------------------------------------------------------------------------
// all-bf16 MFMA NT GEMM: out[m,n] = sum_k Xb[m,k] * Wb[n,k]
// Xb: n_rows x STRB bf16 (pads zero), Wb: 320 x 320 bf16 (pads zero)
// out_bf16 ? u16 rows stride STRB (pads zeroed) : fp32 rows stride H
// ---------------------------------------------------------------------------
#define BM 128
#define BN 64
#define BK 32
#define LDP 40

__global__ __launch_bounds__(256) void k_gemm_bb(const u16* __restrict__ Xb,
                                                 const u16* __restrict__ Wb,
                                                 void* __restrict__ outp, int out_bf16,
                                                 int n_rows) {
    __shared__ __align__(16) short As[BM * LDP];
    __shared__ __align__(16) short Bs[BN * LDP];
    const int tid = threadIdx.x;
    const int bm = blockIdx.x * BM;
    const int bn = blockIdx.y * BN;
    const int lane = tid & 63;
    const int wid = tid >> 6;
    const int wr = wid >> 1;
    const int wc = wid & 1;
    const int lrow = lane & 15;
    const int kgrp = lane >> 4;

    f32x4 acc[4][2];
    #pragma unroll
    for (int m = 0; m < 4; m++)
        #pragma unroll
        for (int n = 0; n < 2; n++) acc[m][n] = (f32x4){0.f, 0.f, 0.f, 0.f};

    for (int k0 = 0; k0 < STRB; k0 += BK) {
        // stage A: 128x32 bf16, 512 chunks of u16x8, 2/thread
        #pragma unroll
        for (int i = 0; i < 2; ++i) {
            int q = tid + i * 256;
            int r = q >> 2, c = (q & 3) << 3;
            int gr = bm + r;
            u16x8 v = {0, 0, 0, 0, 0, 0, 0, 0};
            if (gr < n_rows) v = *(const u16x8*)&Xb[(long)gr * STRB + k0 + c];
            *(u16x8*)&As[r * LDP + c] = v;
        }
        // stage B: 64x32 bf16, 256 chunks, 1/thread (Wb rows 0..319 all valid)
        {
            int r = tid >> 2, c = (tid & 3) << 3;
            u16x8 v = *(const u16x8*)&Wb[(long)(bn + r) * STRB + k0 + c];
            *(u16x8*)&Bs[r * LDP + c] = v;
        }
        __syncthreads();

        bf16x8 af[4], bfr[2];
        #pragma unroll
        for (int m = 0; m < 4; m++) {
            int row = wr * 64 + m * 16 + lrow;
            af[m] = *(const bf16x8*)&As[row * LDP + kgrp * 8];
        }
        #pragma unroll
        for (int n = 0; n < 2; n++) {
            int col = wc * 32 + n * 16 + lrow;
            bfr[n] = *(const bf16x8*)&Bs[col * LDP + kgrp * 8];
        }
        #pragma unroll
        for (int m = 0; m < 4; m++)
            #pragma unroll
            for (int n = 0; n < 2; n++)
                acc[m][n] = __builtin_amdgcn_mfma_f32_16x16x32_bf16(af[m], bfr[n], acc[m][n], 0, 0, 0);
        __syncthreads();
    }

    if (!out_bf16) {
        float* out = (float*)outp;
        #pragma unroll
        for (int m = 0; m < 4; m++)
            #pragma unroll
            for (int n = 0; n < 2; n++) {
                int gc = bn + wc * 32 + n * 16 + lrow;
                if (gc >= H) continue;
                #pragma unroll
                for (int r = 0; r < 4; r++) {
                    int gr = bm + wr * 64 + m * 16 + kgrp * 4 + r;
                    if (gr < n_rows) out[(long)gr * H + gc] = acc[m][n][r];
                }
            }
    } else {
        u16* out = (u16*)outp;
        #pragma unroll
        for (int m = 0; m < 4; m++)
            #pragma unroll
            for (int n = 0; n < 2; n++) {
                int gc = bn + wc * 32 + n * 16 + lrow;
                if (gc >= STRB) continue;
                #pragma unroll
                for (int r = 0; r < 4; r++) {
                    int gr = bm + wr * 64 + m * 16 + kgrp * 4 + r;
                    if (gr < n_rows) out[(long)gr * STRB + gc] = (gc < H) ? f2b(acc[m][n][r]) : 0;
                }
            }
    }
}

// ---------------------------------------------------------------------------
// GCN gather from bf16 rows, 6 edge-streams x 40 chunks
// ---------------------------------------------------------------------------
__global__ __launch_bounds__(256) void k_gcn_gather_b(const u16* __restrict__ xb,
                                                      const float* __restrict__ dinv,
                                                      const int* __restrict__ offs,
                                                      const int* __restrict__ csr,
                                                      float* __restrict__ out) {
    int i = blockIdx.x;
    int t = threadIdx.x;
    int esub = t / NCH;
    int chunk = t - esub * NCH;
    bool active = (t < ACT);
    int start = offs[i], end = offs[i + 1];
    __shared__ float wsh[256];
    __shared__ int ssh[256];
    __shared__ float redbuf[NS * STRB];
    float accv[8] = {0.f, 0.f, 0.f, 0.f, 0.f, 0.f, 0.f, 0.f};
    float di = dinv[i];
    for (int cbase = start; cbase < end; cbase += 256) {
        int p = cbase + t;
        if (p < end) {
            int src = csr[p];
            ssh[t] = src;
            wsh[t] = di * dinv[src];
        }
        __syncthreads();
        int cnt = min(256, end - cbase);
        if (active) {
            for (int q = esub; q < cnt; q += NS) {
                float w = wsh[q];
                const u16* row = xb + (long)ssh[q] * STRB;
                u16x8 v = *(const u16x8*)&row[chunk * 8];
                #pragma unroll
                for (int j = 0; j < 8; j++) accv[j] += w * b2f(v[j]);
            }
        }
        __syncthreads();
    }
    if (active) {
        #pragma unroll
        for (int j = 0; j < 8; j++) redbuf[esub * STRB + chunk * 8 + j] = accv[j];
    }
    __syncthreads();
    for (int c = t; c < H; c += 256) {
        float s = redbuf[c] + redbuf[STRB + c] + redbuf[2 * STRB + c]
                + redbuf[3 * STRB + c] + redbuf[4 * STRB + c] + redbuf[5 * STRB + c];
        out[(long)i * H + c] = fmaxf(s, 0.f);
    }
}

// ---------------------------------------------------------------------------
// dual dot
// ---------------------------------------------------------------------------
__global__ void k_dual_dot(const float* __restrict__ x, long x_stride,
                           const float* __restrict__ ai, const float* __restrict__ aj,
                           float* __restrict__ s_i, float* __restrict__ s_j, int n) {
    int wave = blockIdx.x * (blockDim.x / WAVE) + (threadIdx.x >> 6);
    int lane = threadIdx.x & 63;
    if (wave >= n) return;
    const float* row = x + (long)wave * x_stride;
    float d0 = 0.f, d1 = 0.f;
    for (int j = lane; j < H; j += WAVE) {
        float v = row[j];
        d0 += v * ai[j];
        d1 += v * aj[j];
    }
    for (int o = 32; o > 0; o >>= 1) { d0 += __shfl_down(d0, o); d1 += __shfl_down(d1, o); }
    if (lane == 0) { s_i[wave] = d0; s_j[wave] = d1; }
}

// ---------------------------------------------------------------------------
// GAT gather from bf16 rows with fused segment-softmax, 6 streams x 40 chunks
// ---------------------------------------------------------------------------
__global__ __launch_bounds__(256) void k_gat_gather_b(const u16* __restrict__ xb,
                                                      const float* __restrict__ s_i_arr,
                                                      const float* __restrict__ s_j_arr,
                                                      const int* __restrict__ offs,
                                                      const int* __restrict__ csr,
                                                      float* __restrict__ out, long out_stride,
                                                      int out_off) {
    int i = blockIdx.x;
    int t = threadIdx.x;
    int esub = t / NCH;
    int chunk = t - esub * NCH;
    bool active = (t < ACT);
    int start = offs[i], end = offs[i + 1];
    int deg = end - start;
    __shared__ float wsh[256];
    __shared__ int ssh[256];
    __shared__ float redm[256];
    __shared__ float reds[256];
    __shared__ float redbuf[NS * STRB];
    float accv[8] = {0.f, 0.f, 0.f, 0.f, 0.f, 0.f, 0.f, 0.f};

    if (deg > 0) {
        float si = s_i_arr[i];
        if (deg <= 256) {
            // fast path: stage scores once
            float sc = 0.f;
            float m_t = -1e30f, s_t = 0.f;
            if (t < deg) {
                int src = csr[start + t];
                sc = si + s_j_arr[src];
                sc = (sc >= 0.f) ? sc : 0.01f * sc;
                m_t = sc; s_t = 1.0f;
                ssh[t] = src;
            }
            redm[t] = m_t; reds[t] = s_t;
            __syncthreads();
            for (int o = 128; o > 0; o >>= 1) {
                if (t < o) {
                    float m1 = redm[t], m2 = redm[t + o];
                    float mm = fmaxf(m1, m2);
                    reds[t] = reds[t] * expf(m1 - mm) + reds[t + o] * expf(m2 - mm);
                    redm[t] = mm;
                }
                __syncthreads();
            }
            float m = redm[0];
            float inv = 1.0f / (reds[0] + 1e-16f);
            if (t < deg) wsh[t] = expf(sc - m) * inv;
            __syncthreads();
            if (active) {
                for (int q = esub; q < deg; q += NS) {
                    float w = wsh[q];
                    const u16* row = xb + (long)ssh[q] * STRB;
                    u16x8 v = *(const u16x8*)&row[chunk * 8];
                    #pragma unroll
                    for (int j = 0; j < 8; j++) accv[j] += w * b2f(v[j]);
                }
            }
        } else {
            // general path: online max/denom, then chunked gather
            float m_t = -1e30f, s_t = 0.f;
            for (int p = start + t; p < end; p += 256) {
                float sc = si + s_j_arr[csr[p]];
                sc = (sc >= 0.f) ? sc : 0.01f * sc;
                if (sc > m_t) { s_t = s_t * expf(m_t - sc) + 1.0f; m_t = sc; }
                else s_t += expf(sc - m_t);
            }
            redm[t] = m_t; reds[t] = s_t;
            __syncthreads();
            for (int o = 128; o > 0; o >>= 1) {
                if (t < o) {
                    float m1 = redm[t], m2 = redm[t + o];
                    float mm = fmaxf(m1, m2);
                    reds[t] = reds[t] * expf(m1 - mm) + reds[t + o] * expf(m2 - mm);
                    redm[t] = mm;
                }
                __syncthreads();
            }
            float m = redm[0];
            float inv = 1.0f / (reds[0] + 1e-16f);
            __syncthreads();
            for (int cbase = start; cbase < end; cbase += 256) {
                int p = cbase + t;
                if (p < end) {
                    int src = csr[p];
                    float sc = si + s_j_arr[src];
                    sc = (sc >= 0.f) ? sc : 0.01f * sc;
                    ssh[t] = src;
                    wsh[t] = expf(sc - m) * inv;
                }
                __syncthreads();
                int cnt = min(256, end - cbase);
                if (active) {
                    for (int q = esub; q < cnt; q += NS) {
                        float w = wsh[q];
                        const u16* row = xb + (long)ssh[q] * STRB;
                        u16x8 v = *(const u16x8*)&row[chunk * 8];
                        #pragma unroll
                        for (int j = 0; j < 8; j++) accv[j] += w * b2f(v[j]);
                    }
                }
                __syncthreads();
            }
        }
    }
    if (active) {
        #pragma unroll
        for (int j = 0; j < 8; j++) redbuf[esub * STRB + chunk * 8 + j] = accv[j];
    }
    __syncthreads();
    for (int c = t; c < H; c += 256) {
        float s = redbuf[c] + redbuf[STRB + c] + redbuf[2 * STRB + c]
                + redbuf[3 * STRB + c] + redbuf[4 * STRB + c] + redbuf[5 * STRB + c];
        out[(long)i * out_stride + out_off + c] = fmaxf(s, 0.f);
    }
}

// ---------------------------------------------------------------------------
// highway elementwise, optional bf16 mirror (stride STRB, pads zeroed)
// ---------------------------------------------------------------------------
__global__ void k_highway(const float* __restrict__ pre, const float* __restrict__ b,
                          const float* __restrict__ xnew, const float* __restrict__ xold,
                          float* __restrict__ out, long out_stride,
                          u16* __restrict__ mirror, int n_rows) {
    long total = (long)n_rows * H;
    long stride = (long)gridDim.x * blockDim.x;
    for (long idx = (long)blockIdx.x * blockDim.x + threadIdx.x; idx < total; idx += stride) {
        long row = idx / H;
        int col = (int)(idx - row * H);
        float g = 1.0f / (1.0f + expf(-(pre[idx] + b[col])));
        float val = g * xnew[idx] + (1.0f - g) * xold[idx];
        out[row * out_stride + col] = val;
        if (mirror) {
            mirror[row * STRB + col] = f2b(val);
            if (col < STRB - H) mirror[row * STRB + H + col] = 0;
        }
    }
}

// ---------------------------------------------------------------------------
// strided fp32 -> padded bf16 conversion
// ---------------------------------------------------------------------------
__global__ void k_conv_b(const float* __restrict__ src, long sstride,
                         u16* __restrict__ dst, int n_rows) {
    long total = (long)n_rows * STRB;
    long stride = (long)gridDim.x * blockDim.x;
    for (long idx = (long)blockIdx.x * blockDim.x + threadIdx.x; idx < total; idx += stride) {
        long row = idx / STRB;
        int col = (int)(idx - row * STRB);
        dst[idx] = (col < H) ? f2b(src[row * sstride + col]) : 0;
    }
}

// ---------------------------------------------------------------------------
// launch
// ---------------------------------------------------------------------------
extern "C" void kernel_launch(void* const* d_in, const int* in_sizes, int n_in,
                              void* d_out, int out_size, void* d_ws, size_t ws_size,
                              hipStream_t stream) {
    const float* x_e     = (const float*)d_in[0];
    const int*   ei_all  = (const int*)d_in[3];
    const float* gcn1_W  = (const float*)d_in[5];
    const float* hw1_W   = (const float*)d_in[6];
    const float* hw1_b   = (const float*)d_in[7];
    const float* gat1_ai = (const float*)d_in[8];
    const float* gat1_aj = (const float*)d_in[9];
    const float* ghw1_W  = (const float*)d_in[10];
    const float* ghw1_b  = (const float*)d_in[11];
    const float* gat2_ai = (const float*)d_in[12];
    const float* gat2_aj = (const float*)d_in[13];
    const float* ghw2_W  = (const float*)d_in[14];
    const float* ghw2_b  = (const float*)d_in[15];
    const float* gat_ai  = (const float*)d_in[16];
    const float* gat_aj  = (const float*)d_in[17];

    const int N = in_sizes[0] / H;
    const int E = in_sizes[3] / 2;
    const int* ei_j = ei_all;
    const int* ei_i = ei_all + E;

    float* out = (float*)d_out;

    size_t NH = (size_t)N * H;
    float* A      = (float*)d_ws;
    float* B      = A + NH;
    float* C      = B + NH;
    float* sbi    = C + NH;
    float* sbj    = sbi + N;
    float* dinv   = sbj + N;
    int*   deg    = (int*)(dinv + N);
    int*   offs   = deg + N;
    int*   cursor = offs + (N + 1);
    int*   csr    = cursor + N;             // E ints
    u16*   wb0    = (u16*)(csr + E);        // 4 x 320x320 bf16 weights
    u16*   wb1    = wb0 + STRB * STRB;
    u16*   wb2    = wb1 + STRB * STRB;
    u16*   wb3    = wb2 + STRB * STRB;

    // bf16 mirrors in dead regions of d_out (120 MB total):
    //   x2b  at d_out[0..32MB)           (alive steps 5..9-GEMM)
    //   x0b/x3b at d_out+60MB..92MB      (x0b: steps 1..5-GEMM; x3b: steps 7..8)
    u16* x2b  = (u16*)d_out;
    u16* x0b  = (u16*)(out + (size_t)15000000);   // 60 MB offset
    u16* x3b  = x0b;
    u16* hb   = (u16*)B;    // GCN h, steps 3-4
    u16* xeb  = (u16*)B;    // xe, steps 9.5-10

    dim3 blk256(256);
    int rowsPerBlock = 256 / WAVE;
    dim3 gridRows((N + rowsPerBlock - 1) / rowsPerBlock);
    dim3 gridNode(N);
    dim3 gridE(2048);
    dim3 gridEW(2048);
    dim3 gridW(100);
    dim3 gridGemm((N + BM - 1) / BM, (STRB + BN - 1) / BN);

    // 1. x0 = l2_normalize(x_e) -> A (fp32) + x0b (bf16)
    hipLaunchKernelGGL(k_l2norm, gridRows, blk256, 0, stream, x_e, A, x0b, N);

    // 2. CSR build + weight conversion
    hipLaunchKernelGGL(k_zero_int, dim3(256), blk256, 0, stream, deg, N);
    hipLaunchKernelGGL(k_count_deg, gridE, blk256, 0, stream, ei_i, deg, E);
    hipLaunchKernelGGL(k_dinv, dim3(256), blk256, 0, stream, deg, dinv, N);
    hipLaunchKernelGGL(k_scan, dim3(1), dim3(1024), 0, stream, deg, offs, cursor, N);
    hipLaunchKernelGGL(k_fill_csr, gridE, blk256, 0, stream, ei_j, ei_i, cursor, csr, E);
    hipLaunchKernelGGL(k_conv_w, gridW, blk256, 0, stream, gcn1_W, wb0);
    hipLaunchKernelGGL(k_conv_w, gridW, blk256, 0, stream, hw1_W, wb1);
    hipLaunchKernelGGL(k_conv_w, gridW, blk256, 0, stream, ghw1_W, wb2);
    hipLaunchKernelGGL(k_conv_w, gridW, blk256, 0, stream, ghw2_W, wb3);

    // 3. hb = bf16(x0 @ gcn1_W.T) -> B (bf16)
    hipLaunchKernelGGL(k_gemm_bb, gridGemm, blk256, 0, stream, x0b, wb0, (void*)hb, 1, N);

    // 4. gcn_out -> C
    hipLaunchKernelGGL(k_gcn_gather_b, gridNode, blk256, 0, stream, hb, dinv, offs, csr, C);

    // 5. pre = x0 @ hw1_W.T -> B ; x2 = hw(x0, gcn_out) -> C (+ mirror x2b)
    hipLaunchKernelGGL(k_gemm_bb, gridGemm, blk256, 0, stream, x0b, wb1, (void*)B, 0, N);
    hipLaunchKernelGGL(k_highway, gridEW, blk256, 0, stream, B, hw1_b, C, A, C, (long)H, x2b, N);

    // 6. GAT1 on x2 -> B
    hipLaunchKernelGGL(k_dual_dot, gridRows, blk256, 0, stream, C, (long)H, gat1_ai, gat1_aj, sbi, sbj, N);
    hipLaunchKernelGGL(k_gat_gather_b, gridNode, blk256, 0, stream, x2b, sbi, sbj, offs, csr, B, (long)H, 0);

    // 7. pre = x2 @ ghw1_W.T -> A ; x3 = hw(x2, gat1_out) -> A (+ mirror x3b)
    hipLaunchKernelGGL(k_gemm_bb, gridGemm, blk256, 0, stream, x2b, wb2, (void*)A, 0, N);
    hipLaunchKernelGGL(k_highway, gridEW, blk256, 0, stream, A, ghw1_b, B, C, A, (long)H, x3b, N);

    // 8. GAT2 on x3 -> B
    hipLaunchKernelGGL(k_dual_dot, gridRows, blk256, 0, stream, A, (long)H, gat2_ai, gat2_aj, sbi, sbj, N);
    hipLaunchKernelGGL(k_gat_gather_b, gridNode, blk256, 0, stream, x3b, sbi, sbj, offs, csr, B, (long)H, 0);

    // 9. pre = x2 @ ghw2_W.T -> A ; xe = hw(x2, gat2_out) -> d_out[:,0:300]
    hipLaunchKernelGGL(k_gemm_bb, gridGemm, blk256, 0, stream, x2b, wb3, (void*)A, 0, N);
    hipLaunchKernelGGL(k_highway, gridEW, blk256, 0, stream, A, ghw2_b, B, C, out, (long)(2 * H), (u16*)nullptr, N);

    // 9.5 xeb = bf16(xe) -> B
    hipLaunchKernelGGL(k_conv_b, gridEW, blk256, 0, stream, out, (long)(2 * H), xeb, N);

    // 10. final GAT on xe -> d_out[:,300:600]
    hipLaunchKernelGGL(k_dual_dot, gridRows, blk256, 0, stream, out, (long)(2 * H), gat_ai, gat_aj, sbi, sbj, N);
    hipLaunchKernelGGL(k_gat_gather_b, gridNode, blk256, 0, stream, xeb, sbi, sbj, offs, csr, out, (long)(2 * H), H);
}

// Round 6
// 979.493 us; speedup vs baseline: 2.3396x; 1.0604x over previous
//
#include <hip/hip_runtime.h>
#include <hip/hip_bf16.h>
#include <math.h>

#define H 300
#define WAVE 64
#define STRB 320   // padded bf16 row stride (640 B; 40 chunks of 16 B)
#define NCH 40     // u16x8 chunks per row
#define NS 6       // edge streams per gather block
#define ACT 240    // NS*NCH active threads

typedef short bf16x8 __attribute__((ext_vector_type(8)));
typedef unsigned short u16;
typedef u16 u16x8 __attribute__((ext_vector_type(8)));
typedef u16 u16x4 __attribute__((ext_vector_type(4)));
typedef short short4v __attribute__((ext_vector_type(4)));
typedef float f32x4 __attribute__((ext_vector_type(4)));

__device__ inline unsigned short f2b(float f) {
    union { float f; unsigned int u; } x; x.f = f;
    unsigned int r = x.u + 0x7FFF + ((x.u >> 16) & 1);
    return (unsigned short)(r >> 16);
}
__device__ inline float b2f(u16 h) {
    union { float f; unsigned int u; } x; x.u = ((unsigned int)h) << 16;
    return x.f;
}

// ---------------------------------------------------------------------------
// l2 normalize rows: one wave per row; writes fp32 + padded bf16 mirror
// ---------------------------------------------------------------------------
__global__ void k_l2norm(const float* __restrict__ x, float* __restrict__ out,
                         u16* __restrict__ outb, int n) {
    int wave = blockIdx.x * (blockDim.x / WAVE) + (threadIdx.x >> 6);
    int lane = threadIdx.x & 63;
    if (wave >= n) return;
    const float* row = x + (long)wave * H;
    float s = 0.f;
    for (int j = lane; j < H; j += WAVE) { float v = row[j]; s += v * v; }
    for (int o = 32; o > 0; o >>= 1) s += __shfl_xor(s, o);
    float sc = 1.0f / fmaxf(sqrtf(s), 1e-12f);
    float* orow = out + (long)wave * H;
    u16* brow = outb + (long)wave * STRB;
    for (int j = lane; j < H; j += WAVE) {
        float v = row[j] * sc;
        orow[j] = v;
        brow[j] = f2b(v);
    }
    for (int j = H + lane; j < STRB; j += WAVE) brow[j] = 0;
}

__global__ void k_zero_int(int* p, int n) {
    int i = blockIdx.x * blockDim.x + threadIdx.x;
    int stride = gridDim.x * blockDim.x;
    for (; i < n; i += stride) p[i] = 0;
}

__global__ void k_count_deg(const int* __restrict__ ei_i, int* __restrict__ deg, int E) {
    int i = blockIdx.x * blockDim.x + threadIdx.x;
    int stride = gridDim.x * blockDim.x;
    for (; i < E; i += stride) atomicAdd(&deg[ei_i[i]], 1);
}

__global__ void k_dinv(const int* __restrict__ deg, float* __restrict__ dinv, int n) {
    int i = blockIdx.x * blockDim.x + threadIdx.x;
    int stride = gridDim.x * blockDim.x;
    for (; i < n; i += stride) {
        int d = deg[i];
        dinv[i] = (d > 0) ? 1.0f / sqrtf((float)d) : 0.0f;
    }
}

__global__ void k_scan(const int* __restrict__ deg, int* __restrict__ offsets,
                       int* __restrict__ cursor, int n) {
    __shared__ int sh[1024];
    __shared__ int carry_sh;
    int tid = threadIdx.x;
    if (tid == 0) carry_sh = 0;
    __syncthreads();
    for (int base = 0; base < n; base += 1024) {
        int v = (base + tid < n) ? deg[base + tid] : 0;
        sh[tid] = v;
        __syncthreads();
        for (int off = 1; off < 1024; off <<= 1) {
            int add = (tid >= off) ? sh[tid - off] : 0;
            __syncthreads();
            sh[tid] += add;
            __syncthreads();
        }
        int total = sh[1023];
        int exc = sh[tid] - v;
        int carry = carry_sh;
        if (base + tid < n) {
            int o = carry + exc;
            offsets[base + tid] = o;
            cursor[base + tid] = o;
        }
        __syncthreads();
        if (tid == 0) carry_sh = carry + total;
        __syncthreads();
    }
    if (tid == 0) offsets[n] = carry_sh;
}

__global__ void k_fill_csr(const int* __restrict__ ei_j, const int* __restrict__ ei_i,
                           int* __restrict__ cursor, int* __restrict__ csr_src, int E) {
    int i = blockIdx.x * blockDim.x + threadIdx.x;
    int stride = gridDim.x * blockDim.x;
    for (; i < E; i += stride) {
        int dst = ei_i[i];
        int pos = atomicAdd(&cursor[dst], 1);
        csr_src[pos] = ei_j[i];
    }
}

// ---------------------------------------------------------------------------
// W fp32 [300][300] -> padded bf16 [320][320], pads zero
// ---------------------------------------------------------------------------
__global__ void k_conv_w(const float* __restrict__ W, u16* __restrict__ Wb) {
    int idx = blockIdx.x * blockDim.x + threadIdx.x;
    int stride = gridDim.x * blockDim.x;
    for (; idx < STRB * STRB; idx += stride) {
        int r = idx / STRB, c = idx - r * STRB;
        Wb[idx] = (r < H && c < H) ? f2b(W[r * H + c]) : 0;
    }
}

// ---------------------------------------------------------------------------
// MFMA NT GEMM with fused epilogue.
// A input: Xb (bf16, stride STRB) if non-null, else Xf (fp32, stride H, cvt on fly)
// mode A (outb != null): write bf16 rows stride STRB (pads zeroed)
// mode B (outb == null): highway epilogue:
//    val = sigmoid(acc + bias[c]) * xnew + (1-sigmoid)*xold
//    optional fp32 out (ostride) + optional bf16 mirror (STRB, pads zeroed)
// ---------------------------------------------------------------------------
#define BM 128
#define BN 64
#define BK 32
#define LDP 40

__global__ __launch_bounds__(256) void k_gemm_fused(
        const u16* __restrict__ Xb, const float* __restrict__ Xf,
        const u16* __restrict__ Wb,
        u16* __restrict__ outb,
        const float* __restrict__ hwbias,
        const float* __restrict__ xnew, const float* __restrict__ xold,
        float* __restrict__ outf, long ostride,
        u16* __restrict__ mirror,
        int n_rows) {
    __shared__ __align__(16) short As[BM * LDP];
    __shared__ __align__(16) short Bs[BN * LDP];
    const int tid = threadIdx.x;
    const int bm = blockIdx.x * BM;
    const int bn = blockIdx.y * BN;
    const int lane = tid & 63;
    const int wid = tid >> 6;
    const int wr = wid >> 1;
    const int wc = wid & 1;
    const int lrow = lane & 15;
    const int kgrp = lane >> 4;

    f32x4 acc[4][2];
    #pragma unroll
    for (int m = 0; m < 4; m++)
        #pragma unroll
        for (int n = 0; n < 2; n++) acc[m][n] = (f32x4){0.f, 0.f, 0.f, 0.f};

    for (int k0 = 0; k0 < STRB; k0 += BK) {
        if (Xb) {
            // bf16 staging: 128x32, 512 u16x8 chunks, 2/thread
            #pragma unroll
            for (int i = 0; i < 2; ++i) {
                int q = tid + i * 256;
                int r = q >> 2, c = (q & 3) << 3;
                int gr = bm + r;
                u16x8 v = {0, 0, 0, 0, 0, 0, 0, 0};
                if (gr < n_rows) v = *(const u16x8*)&Xb[(long)gr * STRB + k0 + c];
                *(u16x8*)&As[r * LDP + c] = v;
            }
        } else {
            // fp32 staging with cvt: 128x32, 1024 quads, 4/thread
            #pragma unroll
            for (int i = 0; i < 4; ++i) {
                int q = tid + i * 256;
                int r = q >> 3, c = (q & 7) << 2;
                int gr = bm + r, gk = k0 + c;
                float v0 = 0.f, v1 = 0.f, v2 = 0.f, v3 = 0.f;
                if (gr < n_rows && gk < H) {
                    const float* p = Xf + (long)gr * H + gk;
                    if (gk + 3 < H) {
                        float4 f = *(const float4*)p;
                        v0 = f.x; v1 = f.y; v2 = f.z; v3 = f.w;
                    } else {
                        v0 = p[0];
                        if (gk + 1 < H) v1 = p[1];
                        if (gk + 2 < H) v2 = p[2];
                    }
                }
                short4v h;
                h[0] = (short)f2b(v0); h[1] = (short)f2b(v1);
                h[2] = (short)f2b(v2); h[3] = (short)f2b(v3);
                *(short4v*)&As[r * LDP + c] = h;
            }
        }
        // W staging: 64x32 bf16, 256 chunks, 1/thread
        {
            int r = tid >> 2, c = (tid & 3) << 3;
            u16x8 v = *(const u16x8*)&Wb[(long)(bn + r) * STRB + k0 + c];
            *(u16x8*)&Bs[r * LDP + c] = v;
        }
        __syncthreads();

        bf16x8 af[4], bfr[2];
        #pragma unroll
        for (int m = 0; m < 4; m++) {
            int row = wr * 64 + m * 16 + lrow;
            af[m] = *(const bf16x8*)&As[row * LDP + kgrp * 8];
        }
        #pragma unroll
        for (int n = 0; n < 2; n++) {
            int col = wc * 32 + n * 16 + lrow;
            bfr[n] = *(const bf16x8*)&Bs[col * LDP + kgrp * 8];
        }
        #pragma unroll
        for (int m = 0; m < 4; m++)
            #pragma unroll
            for (int n = 0; n < 2; n++)
                acc[m][n] = __builtin_amdgcn_mfma_f32_16x16x32_bf16(af[m], bfr[n], acc[m][n], 0, 0, 0);
        __syncthreads();
    }

    if (outb) {
        #pragma unroll
        for (int m = 0; m < 4; m++)
            #pragma unroll
            for (int n = 0; n < 2; n++) {
                int gc = bn + wc * 32 + n * 16 + lrow;
                if (gc >= STRB) continue;
                #pragma unroll
                for (int r = 0; r < 4; r++) {
                    int gr = bm + wr * 64 + m * 16 + kgrp * 4 + r;
                    if (gr < n_rows) outb[(long)gr * STRB + gc] = (gc < H) ? f2b(acc[m][n][r]) : 0;
                }
            }
    } else {
        #pragma unroll
        for (int m = 0; m < 4; m++)
            #pragma unroll
            for (int n = 0; n < 2; n++) {
                int gc = bn + wc * 32 + n * 16 + lrow;
                if (gc >= STRB) continue;
                bool colv = (gc < H);
                float bb = colv ? hwbias[gc] : 0.f;
                #pragma unroll
                for (int r = 0; r < 4; r++) {
                    int gr = bm + wr * 64 + m * 16 + kgrp * 4 + r;
                    if (gr >= n_rows) continue;
                    if (colv) {
                        float pre = acc[m][n][r] + bb;
                        float g = 1.0f / (1.0f + __expf(-pre));
                        long off = (long)gr * H + gc;
                        float val = g * xnew[off] + (1.0f - g) * xold[off];
                        if (outf) outf[(long)gr * ostride + gc] = val;
                        if (mirror) mirror[(long)gr * STRB + gc] = f2b(val);
                    } else if (mirror) {
                        mirror[(long)gr * STRB + gc] = 0;
                    }
                }
            }
    }
}

// ---------------------------------------------------------------------------
// GCN gather from bf16 rows, 6 edge-streams x 40 chunks
// ---------------------------------------------------------------------------
__global__ __launch_bounds__(256) void k_gcn_gather_b(const u16* __restrict__ xb,
                                                      const float* __restrict__ dinv,
                                                      const int* __restrict__ offs,
                                                      const int* __restrict__ csr,
                                                      float* __restrict__ out) {
    int i = blockIdx.x;
    int t = threadIdx.x;
    int esub = t / NCH;
    int chunk = t - esub * NCH;
    bool active = (t < ACT);
    int start = offs[i], end = offs[i + 1];
    __shared__ float wsh[256];
    __shared__ int ssh[256];
    __shared__ float redbuf[NS * STRB];
    float accv[8] = {0.f, 0.f, 0.f, 0.f, 0.f, 0.f, 0.f, 0.f};
    float di = dinv[i];
    for (int cbase = start; cbase < end; cbase += 256) {
        int p = cbase + t;
        if (p < end) {
            int src = csr[p];
            ssh[t] = src;
            wsh[t] = di * dinv[src];
        }
        __syncthreads();
        int cnt = min(256, end - cbase);
        if (active) {
            for (int q = esub; q < cnt; q += NS) {
                float w = wsh[q];
                const u16* row = xb + (long)ssh[q] * STRB;
                u16x8 v = *(const u16x8*)&row[chunk * 8];
                #pragma unroll
                for (int j = 0; j < 8; j++) accv[j] += w * b2f(v[j]);
            }
        }
        __syncthreads();
    }
    if (active) {
        #pragma unroll
        for (int j = 0; j < 8; j++) redbuf[esub * STRB + chunk * 8 + j] = accv[j];
    }
    __syncthreads();
    for (int c = t; c < H; c += 256) {
        float s = redbuf[c] + redbuf[STRB + c] + redbuf[2 * STRB + c]
                + redbuf[3 * STRB + c] + redbuf[4 * STRB + c] + redbuf[5 * STRB + c];
        out[(long)i * H + c] = fmaxf(s, 0.f);
    }
}

// ---------------------------------------------------------------------------
// dual dot from bf16 mirror: one wave per row
// ---------------------------------------------------------------------------
__global__ void k_dual_dot_b(const u16* __restrict__ xb,
                             const float* __restrict__ ai, const float* __restrict__ aj,
                             float* __restrict__ s_i, float* __restrict__ s_j, int n) {
    int wave = blockIdx.x * (blockDim.x / WAVE) + (threadIdx.x >> 6);
    int lane = threadIdx.x & 63;
    if (wave >= n) return;
    const u16* row = xb + (long)wave * STRB;
    float d0 = 0.f, d1 = 0.f;
    {
        u16x4 v = *(const u16x4*)&row[lane * 4];
        float4 a4 = *(const float4*)&ai[lane * 4];
        float4 j4 = *(const float4*)&aj[lane * 4];
        float x0 = b2f(v[0]), x1 = b2f(v[1]), x2 = b2f(v[2]), x3 = b2f(v[3]);
        d0 = x0 * a4.x + x1 * a4.y + x2 * a4.z + x3 * a4.w;
        d1 = x0 * j4.x + x1 * j4.y + x2 * j4.z + x3 * j4.w;
    }
    if (lane < 11) {  // cols 256..299 (44 elems = 11 lanes x 4)
        u16x4 v = *(const u16x4*)&row[256 + lane * 4];
        float4 a4 = *(const float4*)&ai[256 + lane * 4];
        float4 j4 = *(const float4*)&aj[256 + lane * 4];
        float x0 = b2f(v[0]), x1 = b2f(v[1]), x2 = b2f(v[2]), x3 = b2f(v[3]);
        d0 += x0 * a4.x + x1 * a4.y + x2 * a4.z + x3 * a4.w;
        d1 += x0 * j4.x + x1 * j4.y + x2 * j4.z + x3 * j4.w;
    }
    for (int o = 32; o > 0; o >>= 1) { d0 += __shfl_down(d0, o); d1 += __shfl_down(d1, o); }
    if (lane == 0) { s_i[wave] = d0; s_j[wave] = d1; }
}

// ---------------------------------------------------------------------------
// GAT gather from bf16 rows with fused segment-softmax, 6 streams x 40 chunks
// deg<=64: wave0 shfl softmax (3 barriers). deg<=256: LDS-tree. else general.
// ---------------------------------------------------------------------------
__global__ __launch_bounds__(256) void k_gat_gather_b(const u16* __restrict__ xb,
                                                      const float* __restrict__ s_i_arr,
                                                      const float* __restrict__ s_j_arr,
                                                      const int* __restrict__ offs,
                                                      const int* __restrict__ csr,
                                                      float* __restrict__ out, long out_stride,
                                                      int out_off) {
    int i = blockIdx.x;
    int t = threadIdx.x;
    int esub = t / NCH;
    int chunk = t - esub * NCH;
    bool active = (t < ACT);
    int start = offs[i], end = offs[i + 1];
    int deg = end - start;
    __shared__ float wsh[256];
    __shared__ int ssh[256];
    __shared__ float redm[256];
    __shared__ float reds[256];
    __shared__ float redbuf[NS * STRB];
    float accv[8] = {0.f, 0.f, 0.f, 0.f, 0.f, 0.f, 0.f, 0.f};

    if (deg > 0) {
        float si = s_i_arr[i];
        if (deg <= 64) {
            // wave0 does staging + shfl softmax
            if (t < 64) {
                float sc = 0.f;
                if (t < deg) {
                    int src = csr[start + t];
                    ssh[t] = src;
                    sc = si + s_j_arr[src];
                    sc = (sc >= 0.f) ? sc : 0.01f * sc;
                }
                float mm = (t < deg) ? sc : -1e30f;
                for (int o = 32; o > 0; o >>= 1) mm = fmaxf(mm, __shfl_xor(mm, o));
                float ex = (t < deg) ? __expf(sc - mm) : 0.f;
                float ss = ex;
                for (int o = 32; o > 0; o >>= 1) ss += __shfl_xor(ss, o);
                if (t < deg) wsh[t] = ex / (ss + 1e-16f);
            }
            __syncthreads();
            if (active) {
                for (int q = esub; q < deg; q += NS) {
                    float w = wsh[q];
                    const u16* row = xb + (long)ssh[q] * STRB;
                    u16x8 v = *(const u16x8*)&row[chunk * 8];
                    #pragma unroll
                    for (int j = 0; j < 8; j++) accv[j] += w * b2f(v[j]);
                }
            }
        } else if (deg <= 256) {
            float sc = 0.f;
            float m_t = -1e30f, s_t = 0.f;
            if (t < deg) {
                int src = csr[start + t];
                sc = si + s_j_arr[src];
                sc = (sc >= 0.f) ? sc : 0.01f * sc;
                m_t = sc; s_t = 1.0f;
                ssh[t] = src;
            }
            redm[t] = m_t; reds[t] = s_t;
            __syncthreads();
            for (int o = 128; o > 0; o >>= 1) {
                if (t < o) {
                    float m1 = redm[t], m2 = redm[t + o];
                    float mm = fmaxf(m1, m2);
                    reds[t] = reds[t] * __expf(m1 - mm) + reds[t + o] * __expf(m2 - mm);
                    redm[t] = mm;
                }
                __syncthreads();
            }
            float m = redm[0];
            float inv = 1.0f / (reds[0] + 1e-16f);
            if (t < deg) wsh[t] = __expf(sc - m) * inv;
            __syncthreads();
            if (active) {
                for (int q = esub; q < deg; q += NS) {
                    float w = wsh[q];
                    const u16* row = xb + (long)ssh[q] * STRB;
                    u16x8 v = *(const u16x8*)&row[chunk * 8];
                    #pragma unroll
                    for (int j = 0; j < 8; j++) accv[j] += w * b2f(v[j]);
                }
            }
        } else {
            // general path: online max/denom, then chunked gather
            float m_t = -1e30f, s_t = 0.f;
            for (int p = start + t; p < end; p += 256) {
                float sc = si + s_j_arr[csr[p]];
                sc = (sc >= 0.f) ? sc : 0.01f * sc;
                if (sc > m_t) { s_t = s_t * __expf(m_t - sc) + 1.0f; m_t = sc; }
                else s_t += __expf(sc - m_t);
            }
            redm[t] = m_t; reds[t] = s_t;
            __syncthreads();
            for (int o = 128; o > 0; o >>= 1) {
                if (t < o) {
                    float m1 = redm[t], m2 = redm[t + o];
                    float mm = fmaxf(m1, m2);
                    reds[t] = reds[t] * __expf(m1 - mm) + reds[t + o] * __expf(m2 - mm);
                    redm[t] = mm;
                }
                __syncthreads();
            }
            float m = redm[0];
            float inv = 1.0f / (reds[0] + 1e-16f);
            __syncthreads();
            for (int cbase = start; cbase < end; cbase += 256) {
                int p = cbase + t;
                if (p < end) {
                    int src = csr[p];
                    float sc = si + s_j_arr[src];
                    sc = (sc >= 0.f) ? sc : 0.01f * sc;
                    ssh[t] = src;
                    wsh[t] = __expf(sc - m) * inv;
                }
                __syncthreads();
                int cnt = min(256, end - cbase);
                if (active) {
                    for (int q = esub; q < cnt; q += NS) {
                        float w = wsh[q];
                        const u16* row = xb + (long)ssh[q] * STRB;
                        u16x8 v = *(const u16x8*)&row[chunk * 8];
                        #pragma unroll
                        for (int j = 0; j < 8; j++) accv[j] += w * b2f(v[j]);
                    }
                }
                __syncthreads();
            }
        }
    }
    if (active) {
        #pragma unroll
        for (int j = 0; j < 8; j++) redbuf[esub * STRB + chunk * 8 + j] = accv[j];
    }
    __syncthreads();
    for (int c = t; c < H; c += 256) {
        float s = redbuf[c] + redbuf[STRB + c] + redbuf[2 * STRB + c]
                + redbuf[3 * STRB + c] + redbuf[4 * STRB + c] + redbuf[5 * STRB + c];
        out[(long)i * out_stride + out_off + c] = fmaxf(s, 0.f);
    }
}

// ---------------------------------------------------------------------------
// launch
// ---------------------------------------------------------------------------
extern "C" void kernel_launch(void* const* d_in, const int* in_sizes, int n_in,
                              void* d_out, int out_size, void* d_ws, size_t ws_size,
                              hipStream_t stream) {
    const float* x_e     = (const float*)d_in[0];
    const int*   ei_all  = (const int*)d_in[3];
    const float* gcn1_W  = (const float*)d_in[5];
    const float* hw1_W   = (const float*)d_in[6];
    const float* hw1_b   = (const float*)d_in[7];
    const float* gat1_ai = (const float*)d_in[8];
    const float* gat1_aj = (const float*)d_in[9];
    const float* ghw1_W  = (const float*)d_in[10];
    const float* ghw1_b  = (const float*)d_in[11];
    const float* gat2_ai = (const float*)d_in[12];
    const float* gat2_aj = (const float*)d_in[13];
    const float* ghw2_W  = (const float*)d_in[14];
    const float* ghw2_b  = (const float*)d_in[15];
    const float* gat_ai  = (const float*)d_in[16];
    const float* gat_aj  = (const float*)d_in[17];

    const int N = in_sizes[0] / H;
    const int E = in_sizes[3] / 2;
    const int* ei_j = ei_all;
    const int* ei_i = ei_all + E;

    float* out = (float*)d_out;

    size_t NH = (size_t)N * H;
    float* A      = (float*)d_ws;
    float* B      = A + NH;
    float* C      = B + NH;
    float* sbi    = C + NH;
    float* sbj    = sbi + N;
    float* dinv   = sbj + N;
    int*   deg    = (int*)(dinv + N);
    int*   offs   = deg + N;
    int*   cursor = offs + (N + 1);
    int*   csr    = cursor + N;             // E ints
    u16*   wb0    = (u16*)(csr + E);        // 4 x 320x320 bf16 weights
    u16*   wb1    = wb0 + STRB * STRB;
    u16*   wb2    = wb1 + STRB * STRB;
    u16*   wb3    = wb2 + STRB * STRB;

    // bf16 mirrors:
    //  x2b  at d_out[0:32MB)        written step5, last read step8 GEMM (step11 GEMM uses C fp32)
    //  x0b  at d_out+60MB           written step1, last read step5 GEMM
    //  x3b  at d_out+60MB           written step8, last read step10 gather
    //  xeb  in A (u16 view)         written step11 (A dead after step5), read steps 12-13
    //  hb   in B (u16 view)         steps 3-4
    u16* x2b = (u16*)d_out;
    u16* x0b = (u16*)(out + (size_t)15000000);   // 60 MB offset
    u16* x3b = x0b;
    u16* xeb = (u16*)A;
    u16* hb  = (u16*)B;

    dim3 blk256(256);
    int rowsPerBlock = 256 / WAVE;
    dim3 gridRows((N + rowsPerBlock - 1) / rowsPerBlock);
    dim3 gridNode(N);
    dim3 gridE(2048);
    dim3 gridW(100);
    dim3 gridGemm((N + BM - 1) / BM, (STRB + BN - 1) / BN);

    // 1. x0 = l2_normalize(x_e) -> A (fp32) + x0b (bf16)
    hipLaunchKernelGGL(k_l2norm, gridRows, blk256, 0, stream, x_e, A, x0b, N);

    // 2. CSR build + weight conversion
    hipLaunchKernelGGL(k_zero_int, dim3(256), blk256, 0, stream, deg, N);
    hipLaunchKernelGGL(k_count_deg, gridE, blk256, 0, stream, ei_i, deg, E);
    hipLaunchKernelGGL(k_dinv, dim3(256), blk256, 0, stream, deg, dinv, N);
    hipLaunchKernelGGL(k_scan, dim3(1), dim3(1024), 0, stream, deg, offs, cursor, N);
    hipLaunchKernelGGL(k_fill_csr, gridE, blk256, 0, stream, ei_j, ei_i, cursor, csr, E);
    hipLaunchKernelGGL(k_conv_w, gridW, blk256, 0, stream, gcn1_W, wb0);
    hipLaunchKernelGGL(k_conv_w, gridW, blk256, 0, stream, hw1_W, wb1);
    hipLaunchKernelGGL(k_conv_w, gridW, blk256, 0, stream, ghw1_W, wb2);
    hipLaunchKernelGGL(k_conv_w, gridW, blk256, 0, stream, ghw2_W, wb3);

    // 3. hb = bf16(x0 @ gcn1_W.T) -> B (bf16)
    hipLaunchKernelGGL(k_gemm_fused, gridGemm, blk256, 0, stream,
                       x0b, (const float*)nullptr, wb0, hb,
                       (const float*)nullptr, (const float*)nullptr, (const float*)nullptr,
                       (float*)nullptr, (long)0, (u16*)nullptr, N);

    // 4. gcn_out -> C
    hipLaunchKernelGGL(k_gcn_gather_b, gridNode, blk256, 0, stream, hb, dinv, offs, csr, C);

    // 5. x2 = hw(x0, gcn_out) fused: pre = x0@hw1_W.T; out C fp32 + mirror x2b
    hipLaunchKernelGGL(k_gemm_fused, gridGemm, blk256, 0, stream,
                       x0b, (const float*)nullptr, wb1, (u16*)nullptr,
                       hw1_b, C, A, C, (long)H, x2b, N);

    // 6. dots for GAT1 from x2b
    hipLaunchKernelGGL(k_dual_dot_b, gridRows, blk256, 0, stream, x2b, gat1_ai, gat1_aj, sbi, sbj, N);

    // 7. GAT1 gather on x2b -> B
    hipLaunchKernelGGL(k_gat_gather_b, gridNode, blk256, 0, stream, x2b, sbi, sbj, offs, csr, B, (long)H, 0);

    // 8. x3 = hw(x2, gat1_out) fused: pre = x2b@ghw1_W.T; mirror x3b only (no fp32)
    hipLaunchKernelGGL(k_gemm_fused, gridGemm, blk256, 0, stream,
                       x2b, (const float*)nullptr, wb2, (u16*)nullptr,
                       ghw1_b, B, C, (float*)nullptr, (long)0, x3b, N);

    // 9. dots for GAT2 from x3b
    hipLaunchKernelGGL(k_dual_dot_b, gridRows, blk256, 0, stream, x3b, gat2_ai, gat2_aj, sbi, sbj, N);

    // 10. GAT2 gather on x3b -> B
    hipLaunchKernelGGL(k_gat_gather_b, gridNode, blk256, 0, stream, x3b, sbi, sbj, offs, csr, B, (long)H, 0);

    // 11. xe = hw(x2, gat2_out) fused: pre = C(fp32)@ghw2_W.T; out d_out[:,0:300] + mirror xeb(A)
    hipLaunchKernelGGL(k_gemm_fused, gridGemm, blk256, 0, stream,
                       (const u16*)nullptr, C, wb3, (u16*)nullptr,
                       ghw2_b, B, C, out, (long)(2 * H), xeb, N);

    // 12. dots for final GAT from xeb
    hipLaunchKernelGGL(k_dual_dot_b, gridRows, blk256, 0, stream, xeb, gat_ai, gat_aj, sbi, sbj, N);

    // 13. final GAT gather on xeb -> d_out[:,300:600]
    hipLaunchKernelGGL(k_gat_gather_b, gridNode, blk256, 0, stream, xeb, sbi, sbj, offs, csr, out, (long)(2 * H), H);
}